// Round 1
// baseline (1615.897 us; speedup 1.0000x reference)
//
#include <hip/hip_runtime.h>

#define D 128
#define NPB 16          // nodes per block in node_update

// ---------------------------------------------------------------------------
// Transpose the four 128x128 weight matrices into workspace so the node
// kernel's k-loop reads W_t[k][j] coalesced across lanes (j = lane).
// grid (64,4), block 256. Tiny (64K elements total).
// ---------------------------------------------------------------------------
__global__ void transpose4_kernel(const float* __restrict__ A,
                                  const float* __restrict__ B,
                                  const float* __restrict__ C,
                                  const float* __restrict__ Dm,
                                  float* __restrict__ oA, float* __restrict__ oB,
                                  float* __restrict__ oC, float* __restrict__ oD) {
    int idx = blockIdx.x * 256 + threadIdx.x;    // 0..16383
    int k = idx >> 7;
    int j = idx & (D - 1);
    const float* s;
    float* o;
    switch (blockIdx.y) {
        case 0: s = A; o = oA; break;
        case 1: s = B; o = oB; break;
        case 2: s = C; o = oC; break;
        default: s = Dm; o = oD; break;
    }
    o[idx] = s[j * D + k];   // o[k][j] = s[j][k]
}

// ---------------------------------------------------------------------------
// Edge scatter: agg[dst] += x[src] - rel[etype]
// One wave (64 lanes) per edge; lane handles a float2 (2 consecutive floats).
// Reads are coalesced 512B per row; atomics are native f32 adds at L2.
// ---------------------------------------------------------------------------
__global__ __launch_bounds__(256) void scatter_kernel(
    const float* __restrict__ x,
    const int* __restrict__ src,
    const int* __restrict__ dst,
    const int* __restrict__ etype,
    const float* __restrict__ rel,
    float* __restrict__ agg,
    int E) {
    int gid = blockIdx.x * 256 + threadIdx.x;
    int e = gid >> 6;          // wave-uniform
    int lane = gid & 63;
    if (e >= E) return;
    int s = src[e];
    int d = dst[e];
    int t = etype[e];
    const float2* xr = (const float2*)(x + (size_t)s * D);
    const float2* rr = (const float2*)(rel + (size_t)t * D);
    float2 xv = xr[lane];
    float2 rv = rr[lane];
    float* ap = agg + (size_t)d * D + lane * 2;
    unsafeAtomicAdd(ap,     xv.x - rv.x);
    unsafeAtomicAdd(ap + 1, xv.y - rv.y);
}

// ---------------------------------------------------------------------------
// Node update: out[n,:] = act( (agg[n,:]+x[n,:]-rel0) @ WIt + x[n,:] @ WOt + b )
// WIt/WOt are pre-transposed: Wt[k*128+j] = W[j*128+k].
// Block: 256 threads = 128 j-columns x 2 node-groups; NPB=16 nodes per block.
// U/X rows staged in LDS; per-k reads of U/X are wave-uniform broadcasts.
// ---------------------------------------------------------------------------
__global__ __launch_bounds__(256) void node_kernel(
    const float* __restrict__ agg,
    const float* __restrict__ x,
    const float* __restrict__ rel0,
    const float* __restrict__ WIt,
    const float* __restrict__ WOt,
    const float* __restrict__ b,
    float* __restrict__ out,
    int do_relu) {
    __shared__ float U[NPB][D];
    __shared__ float X[NPB][D];
    int tid = threadIdx.x;
    int nbase = blockIdx.x * NPB;

    // cooperative stage: NPB*128 = 2048 elems per array, 256 threads -> 8 each
    for (int i = tid; i < NPB * D; i += 256) {
        int nn = i >> 7;
        int k = i & (D - 1);
        size_t gidx = (size_t)(nbase + nn) * D + k;
        float xv = x[gidx];
        X[nn][k] = xv;
        U[nn][k] = agg[gidx] + xv - rel0[k];
    }
    __syncthreads();

    int j = tid & (D - 1);
    int g = tid >> 7;            // 0 or 1 -> nodes [g*8, g*8+8)
    float bj = b[j];
    float acc[8];
#pragma unroll
    for (int i = 0; i < 8; i++) acc[i] = bj;

    for (int k = 0; k < D; k++) {
        float wi = WIt[k * D + j];
        float wo = WOt[k * D + j];
#pragma unroll
        for (int i = 0; i < 8; i++) {
            acc[i] = fmaf(U[g * 8 + i][k], wi, acc[i]);
            acc[i] = fmaf(X[g * 8 + i][k], wo, acc[i]);
        }
    }

#pragma unroll
    for (int i = 0; i < 8; i++) {
        float v = acc[i];
        if (do_relu) v = fmaxf(v, 0.f);
        out[(size_t)(nbase + g * 8 + i) * D + j] = v;
    }
}

extern "C" void kernel_launch(void* const* d_in, const int* in_sizes, int n_in,
                              void* d_out, int out_size, void* d_ws, size_t ws_size,
                              hipStream_t stream) {
    const float* x    = (const float*)d_in[0];
    const int*   ei   = (const int*)d_in[1];
    const int*   et   = (const int*)d_in[2];
    const float* WI1  = (const float*)d_in[3];
    const float* WO1  = (const float*)d_in[4];
    const float* rel1 = (const float*)d_in[5];
    const float* b1   = (const float*)d_in[6];
    const float* WI2  = (const float*)d_in[7];
    const float* WO2  = (const float*)d_in[8];
    const float* rel2 = (const float*)d_in[9];
    const float* b2   = (const float*)d_in[10];

    const int E = in_sizes[2];          // 800000
    const int N = in_sizes[0] / D;      // 50000
    const int* src = ei;
    const int* dst = ei + E;

    float* ws   = (float*)d_ws;
    float* agg  = ws;                         // N*D
    float* h    = agg + (size_t)N * D;        // N*D
    float* WI1t = h + (size_t)N * D;          // 128*128 each
    float* WO1t = WI1t + D * D;
    float* WI2t = WO1t + D * D;
    float* WO2t = WI2t + D * D;

    // transpose all four weight matrices
    transpose4_kernel<<<dim3(64, 4), 256, 0, stream>>>(
        WI1, WO1, WI2, WO2, WI1t, WO1t, WI2t, WO2t);

    const int scatter_blocks = (E * 64 + 255) / 256;
    const int node_blocks = N / NPB;   // 50000/16 = 3125 exactly

    // ---- layer 1 ----
    hipMemsetAsync(agg, 0, (size_t)N * D * sizeof(float), stream);
    scatter_kernel<<<scatter_blocks, 256, 0, stream>>>(x, src, dst, et, rel1, agg, E);
    node_kernel<<<node_blocks, 256, 0, stream>>>(agg, x, rel1, WI1t, WO1t, b1, h, 1);

    // ---- layer 2 ----
    hipMemsetAsync(agg, 0, (size_t)N * D * sizeof(float), stream);
    scatter_kernel<<<scatter_blocks, 256, 0, stream>>>(h, src, dst, et, rel2, agg, E);
    node_kernel<<<node_blocks, 256, 0, stream>>>(agg, h, rel2, WI2t, WO2t, b2, (float*)d_out, 0);
}

// Round 2
// 638.016 us; speedup vs baseline: 2.5327x; 2.5327x over previous
//
#include <hip/hip_runtime.h>

#define D 128
#define NPB 16          // nodes per block in node_update

// ---------------------------------------------------------------------------
// Transpose the four 128x128 weight matrices into workspace so the node
// kernel's k-loop reads W_t[k][j] coalesced across lanes (j = lane).
// ---------------------------------------------------------------------------
__global__ void transpose4_kernel(const float* __restrict__ A,
                                  const float* __restrict__ B,
                                  const float* __restrict__ C,
                                  const float* __restrict__ Dm,
                                  float* __restrict__ oA, float* __restrict__ oB,
                                  float* __restrict__ oC, float* __restrict__ oD) {
    int idx = blockIdx.x * 256 + threadIdx.x;    // 0..16383
    int k = idx >> 7;
    int j = idx & (D - 1);
    const float* s;
    float* o;
    switch (blockIdx.y) {
        case 0: s = A; o = oA; break;
        case 1: s = B; o = oB; break;
        case 2: s = C; o = oC; break;
        default: s = Dm; o = oD; break;
    }
    o[idx] = s[j * D + k];   // o[k][j] = s[j][k]
}

// ---------------------------------------------------------------------------
// CSR build step 1: histogram of dst
// ---------------------------------------------------------------------------
__global__ __launch_bounds__(256) void hist_kernel(const int* __restrict__ dst,
                                                   int* __restrict__ counts, int E) {
    int e = blockIdx.x * 256 + threadIdx.x;
    if (e < E) atomicAdd(&counts[dst[e]], 1);
}

// ---------------------------------------------------------------------------
// CSR build step 2: exclusive scan of counts -> row_ptr and cursor.
// Single block of 1024; each thread owns a contiguous chunk. N=50000 -> 49/thread.
// ---------------------------------------------------------------------------
__global__ __launch_bounds__(1024) void scan_kernel(const int* __restrict__ counts,
                                                    int* __restrict__ row_ptr,
                                                    int* __restrict__ cursor, int N) {
    __shared__ int partial[1024];
    int tid = threadIdx.x;
    int per = (N + 1023) / 1024;
    int beg = tid * per;
    int end = beg + per; if (end > N) end = N;
    int s = 0;
    for (int i = beg; i < end; ++i) s += counts[i];
    partial[tid] = s;
    __syncthreads();
    // Hillis-Steele inclusive scan in LDS
    for (int off = 1; off < 1024; off <<= 1) {
        int v = (tid >= off) ? partial[tid - off] : 0;
        __syncthreads();
        partial[tid] += v;
        __syncthreads();
    }
    int run = (tid > 0) ? partial[tid - 1] : 0;   // exclusive prefix of my chunk
    for (int i = beg; i < end; ++i) {
        row_ptr[i] = run;
        cursor[i]  = run;
        run += counts[i];
    }
    if (tid == 1023) row_ptr[N] = partial[1023];  // == E
}

// ---------------------------------------------------------------------------
// CSR build step 3: place each edge at its slot; col[pos] = (src, etype)
// ---------------------------------------------------------------------------
__global__ __launch_bounds__(256) void reorder_kernel(const int* __restrict__ src,
                                                      const int* __restrict__ dst,
                                                      const int* __restrict__ et,
                                                      int* __restrict__ cursor,
                                                      int2* __restrict__ col, int E) {
    int e = blockIdx.x * 256 + threadIdx.x;
    if (e < E) {
        int pos = atomicAdd(&cursor[dst[e]], 1);
        col[pos] = make_int2(src[e], et[e]);
    }
}

// ---------------------------------------------------------------------------
// Gather: agg[n,:] = sum_{e in CSR row n} (x[src_e,:] - rel[et_e,:])
// One wave per node; lane holds a float2 (the full 128-f32 row across 64 lanes).
// 2-edge unroll for memory-level parallelism on the L3-latency chain.
// No atomics, one coalesced 512B write per node.
// ---------------------------------------------------------------------------
__global__ __launch_bounds__(256) void gather_kernel(const float* __restrict__ x,
                                                     const int2* __restrict__ col,
                                                     const int* __restrict__ row_ptr,
                                                     const float* __restrict__ rel,
                                                     float* __restrict__ agg, int N) {
    int n = blockIdx.x * 4 + (threadIdx.x >> 6);
    if (n >= N) return;
    int lane = threadIdx.x & 63;
    int beg = row_ptr[n];
    int end = row_ptr[n + 1];
    const float2* x2 = (const float2*)x;
    const float2* r2 = (const float2*)rel;
    float sx = 0.f, sy = 0.f;
    int e = beg;
    for (; e + 1 < end; e += 2) {
        int2 e0 = col[e];
        int2 e1 = col[e + 1];
        float2 xv0 = x2[(size_t)e0.x * 64 + lane];
        float2 rv0 = r2[(size_t)e0.y * 64 + lane];
        float2 xv1 = x2[(size_t)e1.x * 64 + lane];
        float2 rv1 = r2[(size_t)e1.y * 64 + lane];
        sx += (xv0.x - rv0.x) + (xv1.x - rv1.x);
        sy += (xv0.y - rv0.y) + (xv1.y - rv1.y);
    }
    if (e < end) {
        int2 e0 = col[e];
        float2 xv0 = x2[(size_t)e0.x * 64 + lane];
        float2 rv0 = r2[(size_t)e0.y * 64 + lane];
        sx += xv0.x - rv0.x;
        sy += xv0.y - rv0.y;
    }
    ((float2*)agg)[(size_t)n * 64 + lane] = make_float2(sx, sy);
}

// ---------------------------------------------------------------------------
// Node update: out[n,:] = act( (agg[n,:]+x[n,:]-rel0) @ WIt + x[n,:] @ WOt + b )
// Safe when out aliases agg: all agg reads complete (barrier) before writes,
// and blocks touch disjoint 16-row slices.
// ---------------------------------------------------------------------------
__global__ __launch_bounds__(256) void node_kernel(
    const float* __restrict__ agg,
    const float* __restrict__ x,
    const float* __restrict__ rel0,
    const float* __restrict__ WIt,
    const float* __restrict__ WOt,
    const float* __restrict__ b,
    float* __restrict__ out,
    int do_relu) {
    __shared__ float U[NPB][D];
    __shared__ float X[NPB][D];
    int tid = threadIdx.x;
    int nbase = blockIdx.x * NPB;

    for (int i = tid; i < NPB * D; i += 256) {
        int nn = i >> 7;
        int k = i & (D - 1);
        size_t gidx = (size_t)(nbase + nn) * D + k;
        float xv = x[gidx];
        X[nn][k] = xv;
        U[nn][k] = agg[gidx] + xv - rel0[k];
    }
    __syncthreads();

    int j = tid & (D - 1);
    int g = tid >> 7;            // 0 or 1 -> nodes [g*8, g*8+8)
    float bj = b[j];
    float acc[8];
#pragma unroll
    for (int i = 0; i < 8; i++) acc[i] = bj;

    for (int k = 0; k < D; k++) {
        float wi = WIt[k * D + j];
        float wo = WOt[k * D + j];
#pragma unroll
        for (int i = 0; i < 8; i++) {
            acc[i] = fmaf(U[g * 8 + i][k], wi, acc[i]);
            acc[i] = fmaf(X[g * 8 + i][k], wo, acc[i]);
        }
    }

#pragma unroll
    for (int i = 0; i < 8; i++) {
        float v = acc[i];
        if (do_relu) v = fmaxf(v, 0.f);
        out[(size_t)(nbase + g * 8 + i) * D + j] = v;
    }
}

extern "C" void kernel_launch(void* const* d_in, const int* in_sizes, int n_in,
                              void* d_out, int out_size, void* d_ws, size_t ws_size,
                              hipStream_t stream) {
    const float* x    = (const float*)d_in[0];
    const int*   ei   = (const int*)d_in[1];
    const int*   et   = (const int*)d_in[2];
    const float* WI1  = (const float*)d_in[3];
    const float* WO1  = (const float*)d_in[4];
    const float* rel1 = (const float*)d_in[5];
    const float* b1   = (const float*)d_in[6];
    const float* WI2  = (const float*)d_in[7];
    const float* WO2  = (const float*)d_in[8];
    const float* rel2 = (const float*)d_in[9];
    const float* b2   = (const float*)d_in[10];

    const int E = in_sizes[2];          // 800000
    const int N = in_sizes[0] / D;      // 50000
    const int* src = ei;
    const int* dst = ei + E;

    // workspace layout
    float* ws   = (float*)d_ws;
    float* h    = ws;                          // N*D floats (25.6 MB)
    float* WI1t = h + (size_t)N * D;           // 4 x 128*128
    float* WO1t = WI1t + D * D;
    float* WI2t = WO1t + D * D;
    float* WO2t = WI2t + D * D;
    int*   counts  = (int*)(WO2t + D * D);     // N
    int*   row_ptr = counts + N;               // N+1
    int*   cursor  = row_ptr + N + 1;          // N
    int2*  col     = (int2*)(cursor + N);      // E int2 (6.4 MB)

    float* agg = (float*)d_out;                // gather output lives in d_out

    const int eb = (E + 255) / 256;

    // ---- CSR build (shared by both layers) ----
    hipMemsetAsync(counts, 0, (size_t)N * sizeof(int), stream);
    transpose4_kernel<<<dim3(64, 4), 256, 0, stream>>>(
        WI1, WO1, WI2, WO2, WI1t, WO1t, WI2t, WO2t);
    hist_kernel<<<eb, 256, 0, stream>>>(dst, counts, E);
    scan_kernel<<<1, 1024, 0, stream>>>(counts, row_ptr, cursor, N);
    reorder_kernel<<<eb, 256, 0, stream>>>(src, dst, et, cursor, col, E);

    const int gather_blocks = (N + 3) / 4;     // 4 nodes (waves) per block
    const int node_blocks = N / NPB;           // 3125

    // ---- layer 1 ----
    gather_kernel<<<gather_blocks, 256, 0, stream>>>(x, col, row_ptr, rel1, agg, N);
    node_kernel<<<node_blocks, 256, 0, stream>>>(agg, x, rel1, WI1t, WO1t, b1, h, 1);

    // ---- layer 2 ----
    gather_kernel<<<gather_blocks, 256, 0, stream>>>(h, col, row_ptr, rel2, agg, N);
    node_kernel<<<node_blocks, 256, 0, stream>>>(agg, h, rel2, WI2t, WO2t, b2, (float*)d_out, 0);
}

// Round 3
// 534.577 us; speedup vs baseline: 3.0228x; 1.1935x over previous
//
#include <hip/hip_runtime.h>

#define D 128
#define NPB 32          // nodes per block in node_kernel

// ---------------------------------------------------------------------------
// prep_w: build Wcat[256][128] per layer:
//   rows 0..127 :  Wcat[k][j]     = WI[j][k]           (agg part)
//   rows 128..255: Wcat[128+k][j] = WI[j][k] + WO[j][k] (x part)
// so node GEMM is A=[agg | x] (Nx256) @ Wcat (256x128).
// ---------------------------------------------------------------------------
__global__ void prep_w(const float* __restrict__ WI1, const float* __restrict__ WO1,
                       const float* __restrict__ WI2, const float* __restrict__ WO2,
                       float* __restrict__ Wcat1, float* __restrict__ Wcat2) {
    int idx = blockIdx.x * 256 + threadIdx.x;   // 0..32767
    int k = idx >> 7;
    int j = idx & (D - 1);
    const float* WI = blockIdx.y ? WI2 : WI1;
    const float* WO = blockIdx.y ? WO2 : WO1;
    float* Wc = blockIdx.y ? Wcat2 : Wcat1;
    float v;
    if (k < D) v = WI[j * D + k];
    else       v = WI[j * D + (k - D)] + WO[j * D + (k - D)];
    Wc[idx] = v;
}

// cvec[j] = b[j] - sum_k WI[j][k]*rel0[k]   (both layers in one 256-thread block)
__global__ void prep_c(const float* __restrict__ WI1, const float* __restrict__ b1,
                       const float* __restrict__ rel1,
                       const float* __restrict__ WI2, const float* __restrict__ b2,
                       const float* __restrict__ rel2,
                       float* __restrict__ c1, float* __restrict__ c2) {
    int tid = threadIdx.x;
    int layer = tid >> 7;
    int j = tid & (D - 1);
    const float* WI = layer ? WI2 : WI1;
    const float* b  = layer ? b2  : b1;
    const float* rl = layer ? rel2 : rel1;   // row 0
    float s = b[j];
    for (int k = 0; k < D; ++k) s = fmaf(-WI[j * D + k], rl[k], s);
    (layer ? c2 : c1)[j] = s;
}

// ---------------------------------------------------------------------------
// CSR build
// ---------------------------------------------------------------------------
__global__ __launch_bounds__(256) void hist_kernel(const int* __restrict__ dst,
                                                   int* __restrict__ counts, int E) {
    int e = blockIdx.x * 256 + threadIdx.x;
    if (e < E) atomicAdd(&counts[dst[e]], 1);
}

__global__ __launch_bounds__(1024) void scan_kernel(const int* __restrict__ counts,
                                                    int* __restrict__ row_ptr,
                                                    int* __restrict__ cursor, int N) {
    __shared__ int partial[1024];
    int tid = threadIdx.x;
    int per = (N + 1023) / 1024;
    int beg = tid * per;
    int end = beg + per; if (end > N) end = N;
    int s = 0;
    for (int i = beg; i < end; ++i) s += counts[i];
    partial[tid] = s;
    __syncthreads();
    for (int off = 1; off < 1024; off <<= 1) {
        int v = (tid >= off) ? partial[tid - off] : 0;
        __syncthreads();
        partial[tid] += v;
        __syncthreads();
    }
    int run = (tid > 0) ? partial[tid - 1] : 0;
    for (int i = beg; i < end; ++i) {
        row_ptr[i] = run;
        cursor[i]  = run;
        run += counts[i];
    }
    if (tid == 1023) row_ptr[N] = partial[1023];
}

// col packed: src | (etype << 17)
__global__ __launch_bounds__(256) void reorder_kernel(const int* __restrict__ src,
                                                      const int* __restrict__ dst,
                                                      const int* __restrict__ et,
                                                      int* __restrict__ cursor,
                                                      int* __restrict__ col, int E) {
    int e = blockIdx.x * 256 + threadIdx.x;
    if (e < E) {
        int pos = atomicAdd(&cursor[dst[e]], 1);
        col[pos] = src[e] | (et[e] << 17);
    }
}

// ---------------------------------------------------------------------------
// Gather: agg[n,:] = sum_{e in row n} (x[src_e,:] - rel[et_e,:])
// 2 nodes per wave (half-wave of 32 lanes per node), float4 per lane,
// 4-edge unroll -> 8 outstanding 16B loads per lane on the L3 chain.
// ---------------------------------------------------------------------------
__global__ __launch_bounds__(256) void gather_kernel(const float* __restrict__ x,
                                                     const int* __restrict__ col,
                                                     const int* __restrict__ row_ptr,
                                                     const float* __restrict__ rel,
                                                     float* __restrict__ agg, int N) {
    int n = blockIdx.x * 8 + (threadIdx.x >> 5);   // 8 half-waves per block
    if (n >= N) return;
    int lane = threadIdx.x & 31;
    int beg = row_ptr[n];
    int end = row_ptr[n + 1];
    const float4* x4 = (const float4*)x;     // row stride 32 float4
    const float4* r4 = (const float4*)rel;
    float4 s = make_float4(0.f, 0.f, 0.f, 0.f);
    int e = beg;
    for (; e + 3 < end; e += 4) {
        int c0 = col[e], c1 = col[e + 1], c2 = col[e + 2], c3 = col[e + 3];
        float4 a0 = x4[(size_t)(c0 & 0x1FFFF) * 32 + lane];
        float4 r0 = r4[(size_t)(c0 >> 17) * 32 + lane];
        float4 a1 = x4[(size_t)(c1 & 0x1FFFF) * 32 + lane];
        float4 r1 = r4[(size_t)(c1 >> 17) * 32 + lane];
        float4 a2 = x4[(size_t)(c2 & 0x1FFFF) * 32 + lane];
        float4 r2 = r4[(size_t)(c2 >> 17) * 32 + lane];
        float4 a3 = x4[(size_t)(c3 & 0x1FFFF) * 32 + lane];
        float4 r3 = r4[(size_t)(c3 >> 17) * 32 + lane];
        s.x += ((a0.x - r0.x) + (a1.x - r1.x)) + ((a2.x - r2.x) + (a3.x - r3.x));
        s.y += ((a0.y - r0.y) + (a1.y - r1.y)) + ((a2.y - r2.y) + (a3.y - r3.y));
        s.z += ((a0.z - r0.z) + (a1.z - r1.z)) + ((a2.z - r2.z) + (a3.z - r3.z));
        s.w += ((a0.w - r0.w) + (a1.w - r1.w)) + ((a2.w - r2.w) + (a3.w - r3.w));
    }
    for (; e < end; ++e) {
        int c = col[e];
        float4 a = x4[(size_t)(c & 0x1FFFF) * 32 + lane];
        float4 r = r4[(size_t)(c >> 17) * 32 + lane];
        s.x += a.x - r.x;
        s.y += a.y - r.y;
        s.z += a.z - r.z;
        s.w += a.w - r.w;
    }
    ((float4*)agg)[(size_t)n * 32 + lane] = s;
}

// ---------------------------------------------------------------------------
// Node GEMM: out[n][j] = relu?( cvec[j] + sum_{k<256} A[n][k]*Wcat[k][j] )
// A = [agg | x]. 32 nodes/block staged in LDS (32x256 = 32KB).
// Thread = (jq = tid&31 -> cols 4jq..4jq+3, ng = tid>>5 -> nodes 4ng..4ng+3).
// Per 2-k step: 32 FMA : 4 ds_read_b64 : 2 L1-hit float4 weight loads.
// Safe when out aliases agg: blocks read only their own rows before writing.
// ---------------------------------------------------------------------------
__global__ __launch_bounds__(256) void node_kernel(
    const float* __restrict__ agg,
    const float* __restrict__ x,
    const float* __restrict__ Wcat,
    const float* __restrict__ cvec,
    float* __restrict__ out,
    int do_relu, int N) {
    __shared__ float A[NPB][256];
    int tid = threadIdx.x;
    int nbase = blockIdx.x * NPB;

    // stage 32 rows: agg -> A[n][0:128], x -> A[n][128:256]
    {
        const float4* agg4 = (const float4*)(agg + (size_t)nbase * D);
        const float4* x4   = (const float4*)(x   + (size_t)nbase * D);
        for (int i = tid; i < NPB * 32; i += 256) {   // 1024 float4 per source
            int nn = i >> 5;
            int q  = i & 31;
            if (nbase + nn < N) {
                float4 va = agg4[i];
                float4 vx = x4[i];
                *((float4*)&A[nn][q * 4])     = va;
                *((float4*)&A[nn][D + q * 4]) = vx;
            }
        }
    }
    __syncthreads();

    int jq = tid & 31;        // col quad
    int ng = tid >> 5;        // node group (0..7)
    const float4* Wc4 = (const float4*)Wcat;   // row k = 32 float4
    float4 cv = ((const float4*)cvec)[jq];
    float4 acc[4];
#pragma unroll
    for (int i = 0; i < 4; ++i) acc[i] = cv;

    for (int k = 0; k < 256; k += 2) {
        float4 w0 = Wc4[k * 32 + jq];
        float4 w1 = Wc4[k * 32 + 32 + jq];
#pragma unroll
        for (int i = 0; i < 4; ++i) {
            float2 a = *(const float2*)&A[ng * 4 + i][k];
            acc[i].x = fmaf(a.y, w1.x, fmaf(a.x, w0.x, acc[i].x));
            acc[i].y = fmaf(a.y, w1.y, fmaf(a.x, w0.y, acc[i].y));
            acc[i].z = fmaf(a.y, w1.z, fmaf(a.x, w0.z, acc[i].z));
            acc[i].w = fmaf(a.y, w1.w, fmaf(a.x, w0.w, acc[i].w));
        }
    }

#pragma unroll
    for (int i = 0; i < 4; ++i) {
        int n = nbase + ng * 4 + i;
        if (n < N) {
            float4 v = acc[i];
            if (do_relu) {
                v.x = fmaxf(v.x, 0.f); v.y = fmaxf(v.y, 0.f);
                v.z = fmaxf(v.z, 0.f); v.w = fmaxf(v.w, 0.f);
            }
            ((float4*)out)[(size_t)n * 32 + jq] = v;
        }
    }
}

extern "C" void kernel_launch(void* const* d_in, const int* in_sizes, int n_in,
                              void* d_out, int out_size, void* d_ws, size_t ws_size,
                              hipStream_t stream) {
    const float* x    = (const float*)d_in[0];
    const int*   ei   = (const int*)d_in[1];
    const int*   et   = (const int*)d_in[2];
    const float* WI1  = (const float*)d_in[3];
    const float* WO1  = (const float*)d_in[4];
    const float* rel1 = (const float*)d_in[5];
    const float* b1   = (const float*)d_in[6];
    const float* WI2  = (const float*)d_in[7];
    const float* WO2  = (const float*)d_in[8];
    const float* rel2 = (const float*)d_in[9];
    const float* b2   = (const float*)d_in[10];

    const int E = in_sizes[2];          // 800000
    const int N = in_sizes[0] / D;      // 50000
    const int* src = ei;
    const int* dst = ei + E;

    // workspace layout
    float* ws    = (float*)d_ws;
    float* h     = ws;                          // N*D floats
    float* Wcat1 = h + (size_t)N * D;           // 256*128
    float* Wcat2 = Wcat1 + 256 * D;
    float* cvec1 = Wcat2 + 256 * D;             // 128
    float* cvec2 = cvec1 + D;
    int*   counts  = (int*)(cvec2 + D);         // N
    int*   row_ptr = counts + N;                // N+1
    int*   cursor  = row_ptr + N + 1;           // N
    int*   col     = cursor + N;                // E packed ints

    float* agg = (float*)d_out;                 // gather output lives in d_out

    const int eb = (E + 255) / 256;

    // ---- prep + CSR build ----
    hipMemsetAsync(counts, 0, (size_t)N * sizeof(int), stream);
    prep_w<<<dim3(128, 2), 256, 0, stream>>>(WI1, WO1, WI2, WO2, Wcat1, Wcat2);
    prep_c<<<1, 256, 0, stream>>>(WI1, b1, rel1, WI2, b2, rel2, cvec1, cvec2);
    hist_kernel<<<eb, 256, 0, stream>>>(dst, counts, E);
    scan_kernel<<<1, 1024, 0, stream>>>(counts, row_ptr, cursor, N);
    reorder_kernel<<<eb, 256, 0, stream>>>(src, dst, et, cursor, col, E);

    const int gather_blocks = (N + 7) / 8;      // 8 nodes per block
    const int node_blocks = (N + NPB - 1) / NPB;

    // ---- layer 1 ----
    gather_kernel<<<gather_blocks, 256, 0, stream>>>(x, col, row_ptr, rel1, agg, N);
    node_kernel<<<node_blocks, 256, 0, stream>>>(agg, x, Wcat1, cvec1, h, 1, N);

    // ---- layer 2 ----
    gather_kernel<<<gather_blocks, 256, 0, stream>>>(h, col, row_ptr, rel2, agg, N);
    node_kernel<<<node_blocks, 256, 0, stream>>>(agg, h, Wcat2, cvec2, (float*)d_out, 0, N);
}

// Round 4
// 430.630 us; speedup vs baseline: 3.7524x; 1.2414x over previous
//
#include <hip/hip_runtime.h>

#define D 128
#define NPB 32          // nodes per block in node_kernel

// ---------------------------------------------------------------------------
// prep_w: build Wcat[256][128] per layer:
//   rows 0..127 :  Wcat[k][j]     = WI[j][k]           (agg part)
//   rows 128..255: Wcat[128+k][j] = WI[j][k] + WO[j][k] (x part)
// so node GEMM is A=[agg | x] (Nx256) @ Wcat (256x128).
// ---------------------------------------------------------------------------
__global__ void prep_w(const float* __restrict__ WI1, const float* __restrict__ WO1,
                       const float* __restrict__ WI2, const float* __restrict__ WO2,
                       float* __restrict__ Wcat1, float* __restrict__ Wcat2) {
    int idx = blockIdx.x * 256 + threadIdx.x;   // 0..32767
    int k = idx >> 7;
    int j = idx & (D - 1);
    const float* WI = blockIdx.y ? WI2 : WI1;
    const float* WO = blockIdx.y ? WO2 : WO1;
    float* Wc = blockIdx.y ? Wcat2 : Wcat1;
    float v;
    if (k < D) v = WI[j * D + k];
    else       v = WI[j * D + (k - D)] + WO[j * D + (k - D)];
    Wc[idx] = v;
}

// cvec[j] = b[j] - sum_k WI[j][k]*rel0[k]   (both layers in one 256-thread block)
__global__ void prep_c(const float* __restrict__ WI1, const float* __restrict__ b1,
                       const float* __restrict__ rel1,
                       const float* __restrict__ WI2, const float* __restrict__ b2,
                       const float* __restrict__ rel2,
                       float* __restrict__ c1, float* __restrict__ c2) {
    int tid = threadIdx.x;
    int layer = tid >> 7;
    int j = tid & (D - 1);
    const float* WI = layer ? WI2 : WI1;
    const float* b  = layer ? b2  : b1;
    const float* rl = layer ? rel2 : rel1;   // row 0
    float s = b[j];
    for (int k = 0; k < D; ++k) s = fmaf(-WI[j * D + k], rl[k], s);
    (layer ? c2 : c1)[j] = s;
}

// ---------------------------------------------------------------------------
// CSR build
// ---------------------------------------------------------------------------
__global__ __launch_bounds__(256) void hist_kernel(const int* __restrict__ dst,
                                                   int* __restrict__ counts, int E) {
    int e = blockIdx.x * 256 + threadIdx.x;
    if (e < E) atomicAdd(&counts[dst[e]], 1);
}

// ---------------------------------------------------------------------------
// 3-phase coalesced scan (N must be a multiple of 4; N=50000 is).
// scan_a: per-block (1024 elems) exclusive scan -> row_ptr local, blockSums.
// scan_b: scan blockSums (<=256 blocks) in one block.
// scan_c: add block offset, mirror into cursor, write row_ptr[N]=E.
// ---------------------------------------------------------------------------
__global__ __launch_bounds__(256) void scan_a(const int* __restrict__ counts,
                                              int* __restrict__ row_ptr,
                                              int* __restrict__ blockSums, int N4) {
    __shared__ int partial[256];
    int tid = threadIdx.x;
    int gi = blockIdx.x * 256 + tid;
    int4 c = make_int4(0, 0, 0, 0);
    if (gi < N4) c = ((const int4*)counts)[gi];
    int s = c.x + c.y + c.z + c.w;
    partial[tid] = s;
    __syncthreads();
    for (int off = 1; off < 256; off <<= 1) {
        int v = (tid >= off) ? partial[tid - off] : 0;
        __syncthreads();
        partial[tid] += v;
        __syncthreads();
    }
    int pre = (tid > 0) ? partial[tid - 1] : 0;
    if (gi < N4) {
        int4 o;
        o.x = pre;
        o.y = o.x + c.x;
        o.z = o.y + c.y;
        o.w = o.z + c.z;
        ((int4*)row_ptr)[gi] = o;
    }
    if (tid == 255) blockSums[blockIdx.x] = partial[255];
}

__global__ __launch_bounds__(256) void scan_b(int* __restrict__ blockSums, int nb) {
    __shared__ int partial[256];
    int tid = threadIdx.x;
    int orig = (tid < nb) ? blockSums[tid] : 0;
    partial[tid] = orig;
    __syncthreads();
    for (int off = 1; off < 256; off <<= 1) {
        int v = (tid >= off) ? partial[tid - off] : 0;
        __syncthreads();
        partial[tid] += v;
        __syncthreads();
    }
    if (tid < nb) blockSums[tid] = partial[tid] - orig;   // exclusive
}

__global__ __launch_bounds__(256) void scan_c(int* __restrict__ row_ptr,
                                              int* __restrict__ cursor,
                                              const int* __restrict__ blockSums,
                                              int N4, int N, int E) {
    int gi = blockIdx.x * 256 + threadIdx.x;
    int off = blockSums[blockIdx.x];
    if (gi < N4) {
        int4 v = ((int4*)row_ptr)[gi];
        v.x += off; v.y += off; v.z += off; v.w += off;
        ((int4*)row_ptr)[gi] = v;
        ((int4*)cursor)[gi] = v;
    }
    if (blockIdx.x == 0 && threadIdx.x == 0) row_ptr[N] = E;
}

// col packed: src | (etype << 17)
__global__ __launch_bounds__(256) void reorder_kernel(const int* __restrict__ src,
                                                      const int* __restrict__ dst,
                                                      const int* __restrict__ et,
                                                      int* __restrict__ cursor,
                                                      int* __restrict__ col, int E) {
    int e = blockIdx.x * 256 + threadIdx.x;
    if (e < E) {
        int pos = atomicAdd(&cursor[dst[e]], 1);
        col[pos] = src[e] | (et[e] << 17);
    }
}

// ---------------------------------------------------------------------------
// Gather: agg[n,:] = sum_{e in row n} (x[src_e,:] - rel[et_e,:])
// 2 nodes per wave (half-wave of 32 lanes per node), float4 per lane,
// 4-edge unroll -> 8 outstanding 16B loads per lane on the L3 chain.
// ---------------------------------------------------------------------------
__global__ __launch_bounds__(256) void gather_kernel(const float* __restrict__ x,
                                                     const int* __restrict__ col,
                                                     const int* __restrict__ row_ptr,
                                                     const float* __restrict__ rel,
                                                     float* __restrict__ agg, int N) {
    int n = blockIdx.x * 8 + (threadIdx.x >> 5);   // 8 half-waves per block
    if (n >= N) return;
    int lane = threadIdx.x & 31;
    int beg = row_ptr[n];
    int end = row_ptr[n + 1];
    const float4* x4 = (const float4*)x;     // row stride 32 float4
    const float4* r4 = (const float4*)rel;
    float4 s = make_float4(0.f, 0.f, 0.f, 0.f);
    int e = beg;
    for (; e + 3 < end; e += 4) {
        int c0 = col[e], c1 = col[e + 1], c2 = col[e + 2], c3 = col[e + 3];
        float4 a0 = x4[(size_t)(c0 & 0x1FFFF) * 32 + lane];
        float4 r0 = r4[(size_t)(c0 >> 17) * 32 + lane];
        float4 a1 = x4[(size_t)(c1 & 0x1FFFF) * 32 + lane];
        float4 r1 = r4[(size_t)(c1 >> 17) * 32 + lane];
        float4 a2 = x4[(size_t)(c2 & 0x1FFFF) * 32 + lane];
        float4 r2 = r4[(size_t)(c2 >> 17) * 32 + lane];
        float4 a3 = x4[(size_t)(c3 & 0x1FFFF) * 32 + lane];
        float4 r3 = r4[(size_t)(c3 >> 17) * 32 + lane];
        s.x += ((a0.x - r0.x) + (a1.x - r1.x)) + ((a2.x - r2.x) + (a3.x - r3.x));
        s.y += ((a0.y - r0.y) + (a1.y - r1.y)) + ((a2.y - r2.y) + (a3.y - r3.y));
        s.z += ((a0.z - r0.z) + (a1.z - r1.z)) + ((a2.z - r2.z) + (a3.z - r3.z));
        s.w += ((a0.w - r0.w) + (a1.w - r1.w)) + ((a2.w - r2.w) + (a3.w - r3.w));
    }
    for (; e < end; ++e) {
        int c = col[e];
        float4 a = x4[(size_t)(c & 0x1FFFF) * 32 + lane];
        float4 r = r4[(size_t)(c >> 17) * 32 + lane];
        s.x += a.x - r.x;
        s.y += a.y - r.y;
        s.z += a.z - r.z;
        s.w += a.w - r.w;
    }
    ((float4*)agg)[(size_t)n * 32 + lane] = s;
}

// ---------------------------------------------------------------------------
// Node GEMM: out[n][j] = relu?( cvec[j] + sum_{k<256} A[n][k]*Wcat[k][j] )
// A = [agg | x]. 32 nodes/block staged in LDS (32x256 = 32KB).
// Safe when out aliases agg: blocks read only their own rows before writing.
// ---------------------------------------------------------------------------
__global__ __launch_bounds__(256) void node_kernel(
    const float* __restrict__ agg,
    const float* __restrict__ x,
    const float* __restrict__ Wcat,
    const float* __restrict__ cvec,
    float* __restrict__ out,
    int do_relu, int N) {
    __shared__ float A[NPB][256];
    int tid = threadIdx.x;
    int nbase = blockIdx.x * NPB;

    {
        const float4* agg4 = (const float4*)(agg + (size_t)nbase * D);
        const float4* x4   = (const float4*)(x   + (size_t)nbase * D);
        for (int i = tid; i < NPB * 32; i += 256) {   // 1024 float4 per source
            int nn = i >> 5;
            int q  = i & 31;
            if (nbase + nn < N) {
                float4 va = agg4[i];
                float4 vx = x4[i];
                *((float4*)&A[nn][q * 4])     = va;
                *((float4*)&A[nn][D + q * 4]) = vx;
            }
        }
    }
    __syncthreads();

    int jq = tid & 31;        // col quad
    int ng = tid >> 5;        // node group (0..7)
    const float4* Wc4 = (const float4*)Wcat;   // row k = 32 float4
    float4 cv = ((const float4*)cvec)[jq];
    float4 acc[4];
#pragma unroll
    for (int i = 0; i < 4; ++i) acc[i] = cv;

    for (int k = 0; k < 256; k += 2) {
        float4 w0 = Wc4[k * 32 + jq];
        float4 w1 = Wc4[k * 32 + 32 + jq];
#pragma unroll
        for (int i = 0; i < 4; ++i) {
            float2 a = *(const float2*)&A[ng * 4 + i][k];
            acc[i].x = fmaf(a.y, w1.x, fmaf(a.x, w0.x, acc[i].x));
            acc[i].y = fmaf(a.y, w1.y, fmaf(a.x, w0.y, acc[i].y));
            acc[i].z = fmaf(a.y, w1.z, fmaf(a.x, w0.z, acc[i].z));
            acc[i].w = fmaf(a.y, w1.w, fmaf(a.x, w0.w, acc[i].w));
        }
    }

#pragma unroll
    for (int i = 0; i < 4; ++i) {
        int n = nbase + ng * 4 + i;
        if (n < N) {
            float4 v = acc[i];
            if (do_relu) {
                v.x = fmaxf(v.x, 0.f); v.y = fmaxf(v.y, 0.f);
                v.z = fmaxf(v.z, 0.f); v.w = fmaxf(v.w, 0.f);
            }
            ((float4*)out)[(size_t)n * 32 + jq] = v;
        }
    }
}

extern "C" void kernel_launch(void* const* d_in, const int* in_sizes, int n_in,
                              void* d_out, int out_size, void* d_ws, size_t ws_size,
                              hipStream_t stream) {
    const float* x    = (const float*)d_in[0];
    const int*   ei   = (const int*)d_in[1];
    const int*   et   = (const int*)d_in[2];
    const float* WI1  = (const float*)d_in[3];
    const float* WO1  = (const float*)d_in[4];
    const float* rel1 = (const float*)d_in[5];
    const float* b1   = (const float*)d_in[6];
    const float* WI2  = (const float*)d_in[7];
    const float* WO2  = (const float*)d_in[8];
    const float* rel2 = (const float*)d_in[9];
    const float* b2   = (const float*)d_in[10];

    const int E = in_sizes[2];          // 800000
    const int N = in_sizes[0] / D;      // 50000
    const int* src = ei;
    const int* dst = ei + E;

    // workspace layout
    float* ws    = (float*)d_ws;
    float* h     = ws;                          // N*D floats
    float* Wcat1 = h + (size_t)N * D;           // 256*128
    float* Wcat2 = Wcat1 + 256 * D;
    float* cvec1 = Wcat2 + 256 * D;             // 128
    float* cvec2 = cvec1 + D;
    int*   counts  = (int*)(cvec2 + D);         // N
    int*   row_ptr = counts + N;                // N+1 (pad to N+4 for int4)
    int*   cursor  = row_ptr + N + 4;           // N
    int*   blockSums = cursor + N;              // <=256
    int*   col     = blockSums + 256;           // E packed ints

    float* agg = (float*)d_out;                 // gather output lives in d_out

    const int eb = (E + 255) / 256;
    const int N4 = N / 4;                       // N=50000 -> 12500 int4
    const int nb = (N4 + 255) / 256;            // 49 blocks

    // ---- prep + CSR build ----
    hipMemsetAsync(counts, 0, (size_t)N * sizeof(int), stream);
    prep_w<<<dim3(128, 2), 256, 0, stream>>>(WI1, WO1, WI2, WO2, Wcat1, Wcat2);
    prep_c<<<1, 256, 0, stream>>>(WI1, b1, rel1, WI2, b2, rel2, cvec1, cvec2);
    hist_kernel<<<eb, 256, 0, stream>>>(dst, counts, E);
    scan_a<<<nb, 256, 0, stream>>>(counts, row_ptr, blockSums, N4);
    scan_b<<<1, 256, 0, stream>>>(blockSums, nb);
    scan_c<<<nb, 256, 0, stream>>>(row_ptr, cursor, blockSums, N4, N, E);
    reorder_kernel<<<eb, 256, 0, stream>>>(src, dst, et, cursor, col, E);

    const int gather_blocks = (N + 7) / 8;      // 8 nodes per block
    const int node_blocks = (N + NPB - 1) / NPB;

    // ---- layer 1 ----
    gather_kernel<<<gather_blocks, 256, 0, stream>>>(x, col, row_ptr, rel1, agg, N);
    node_kernel<<<node_blocks, 256, 0, stream>>>(agg, x, Wcat1, cvec1, h, 1, N);

    // ---- layer 2 ----
    gather_kernel<<<gather_blocks, 256, 0, stream>>>(h, col, row_ptr, rel2, agg, N);
    node_kernel<<<node_blocks, 256, 0, stream>>>(agg, h, Wcat2, cvec2, (float*)d_out, 0, N);
}

// Round 5
// 395.779 us; speedup vs baseline: 4.0828x; 1.0881x over previous
//
#include <hip/hip_runtime.h>

#define D 128
#define NPB 32          // nodes per block in node_kernel
#define KC 64           // k-chunk in node_kernel

// bf16 helpers: packed storage is little-endian pairs in a uint
__device__ __forceinline__ float blo(unsigned w) { return __uint_as_float(w << 16); }
__device__ __forceinline__ float bhi(unsigned w) { return __uint_as_float(w & 0xFFFF0000u); }
__device__ __forceinline__ unsigned bpack(float a, float b) {   // RNE
    unsigned ua = __float_as_uint(a), ub = __float_as_uint(b);
    ua += 0x7FFFu + ((ua >> 16) & 1u);
    ub += 0x7FFFu + ((ub >> 16) & 1u);
    return (ua >> 16) | (ub & 0xFFFF0000u);
}

// ---------------------------------------------------------------------------
// prep_w: Wcat[256][128]: rows 0..127 = WI^T (agg part),
// rows 128..255 = (WI+WO)^T (x part). Node GEMM = [agg|x] @ Wcat.
// ---------------------------------------------------------------------------
__global__ void prep_w(const float* __restrict__ WI1, const float* __restrict__ WO1,
                       const float* __restrict__ WI2, const float* __restrict__ WO2,
                       float* __restrict__ Wcat1, float* __restrict__ Wcat2) {
    int idx = blockIdx.x * 256 + threadIdx.x;   // 0..32767
    int k = idx >> 7;
    int j = idx & (D - 1);
    const float* WI = blockIdx.y ? WI2 : WI1;
    const float* WO = blockIdx.y ? WO2 : WO1;
    float* Wc = blockIdx.y ? Wcat2 : Wcat1;
    float v;
    if (k < D) v = WI[j * D + k];
    else       v = WI[j * D + (k - D)] + WO[j * D + (k - D)];
    Wc[idx] = v;
}

// cvec[j] = b[j] - sum_k WI[j][k]*rel0[k]
__global__ void prep_c(const float* __restrict__ WI1, const float* __restrict__ b1,
                       const float* __restrict__ rel1,
                       const float* __restrict__ WI2, const float* __restrict__ b2,
                       const float* __restrict__ rel2,
                       float* __restrict__ c1, float* __restrict__ c2) {
    int tid = threadIdx.x;
    int layer = tid >> 7;
    int j = tid & (D - 1);
    const float* WI = layer ? WI2 : WI1;
    const float* b  = layer ? b2  : b1;
    const float* rl = layer ? rel2 : rel1;   // row 0
    float s = b[j];
    for (int k = 0; k < D; ++k) s = fmaf(-WI[j * D + k], rl[k], s);
    (layer ? c2 : c1)[j] = s;
}

// fp32 -> packed bf16 copy (for gather's read traffic)
__global__ __launch_bounds__(256) void conv_bf16(const float* __restrict__ x,
                                                 unsigned* __restrict__ xb, int n4) {
    int i = blockIdx.x * 256 + threadIdx.x;
    if (i < n4) {
        float4 v = ((const float4*)x)[i];
        uint2 o;
        o.x = bpack(v.x, v.y);
        o.y = bpack(v.z, v.w);
        ((uint2*)xb)[i] = o;
    }
}

// ---------------------------------------------------------------------------
// CSR build
// ---------------------------------------------------------------------------
__global__ __launch_bounds__(256) void hist_kernel(const int* __restrict__ dst,
                                                   int* __restrict__ counts, int E) {
    int e = blockIdx.x * 256 + threadIdx.x;
    if (e < E) atomicAdd(&counts[dst[e]], 1);
}

__global__ __launch_bounds__(256) void scan_a(const int* __restrict__ counts,
                                              int* __restrict__ row_ptr,
                                              int* __restrict__ blockSums, int N4) {
    __shared__ int partial[256];
    int tid = threadIdx.x;
    int gi = blockIdx.x * 256 + tid;
    int4 c = make_int4(0, 0, 0, 0);
    if (gi < N4) c = ((const int4*)counts)[gi];
    int s = c.x + c.y + c.z + c.w;
    partial[tid] = s;
    __syncthreads();
    for (int off = 1; off < 256; off <<= 1) {
        int v = (tid >= off) ? partial[tid - off] : 0;
        __syncthreads();
        partial[tid] += v;
        __syncthreads();
    }
    int pre = (tid > 0) ? partial[tid - 1] : 0;
    if (gi < N4) {
        int4 o;
        o.x = pre;
        o.y = o.x + c.x;
        o.z = o.y + c.y;
        o.w = o.z + c.z;
        ((int4*)row_ptr)[gi] = o;
    }
    if (tid == 255) blockSums[blockIdx.x] = partial[255];
}

__global__ __launch_bounds__(256) void scan_b(int* __restrict__ blockSums, int nb) {
    __shared__ int partial[256];
    int tid = threadIdx.x;
    int orig = (tid < nb) ? blockSums[tid] : 0;
    partial[tid] = orig;
    __syncthreads();
    for (int off = 1; off < 256; off <<= 1) {
        int v = (tid >= off) ? partial[tid - off] : 0;
        __syncthreads();
        partial[tid] += v;
        __syncthreads();
    }
    if (tid < nb) blockSums[tid] = partial[tid] - orig;   // exclusive
}

__global__ __launch_bounds__(256) void scan_c(int* __restrict__ row_ptr,
                                              int* __restrict__ cursor,
                                              const int* __restrict__ blockSums,
                                              int N4, int N, int E) {
    int gi = blockIdx.x * 256 + threadIdx.x;
    int off = blockSums[blockIdx.x];
    if (gi < N4) {
        int4 v = ((int4*)row_ptr)[gi];
        v.x += off; v.y += off; v.z += off; v.w += off;
        ((int4*)row_ptr)[gi] = v;
        ((int4*)cursor)[gi] = v;
    }
    if (blockIdx.x == 0 && threadIdx.x == 0) row_ptr[N] = E;
}

// col packed: src | (etype << 17)
__global__ __launch_bounds__(256) void reorder_kernel(const int* __restrict__ src,
                                                      const int* __restrict__ dst,
                                                      const int* __restrict__ et,
                                                      int* __restrict__ cursor,
                                                      int* __restrict__ col, int E) {
    int e = blockIdx.x * 256 + threadIdx.x;
    if (e < E) {
        int pos = atomicAdd(&cursor[dst[e]], 1);
        col[pos] = src[e] | (et[e] << 17);
    }
}

// ---------------------------------------------------------------------------
// Gather (bf16 node features, fp32 rel, fp32 accumulate/output):
// agg[n,:] = sum_{e in row n} (xb[src_e,:] - rel[et_e,:])
// Half-wave (32 lanes) per node; lane owns dims 4L..4L+3 (uint2 = 4 bf16).
// ---------------------------------------------------------------------------
__global__ __launch_bounds__(256) void gather_kernel(const unsigned* __restrict__ xb,
                                                     const int* __restrict__ col,
                                                     const int* __restrict__ row_ptr,
                                                     const float* __restrict__ rel,
                                                     float* __restrict__ agg, int N) {
    int n = blockIdx.x * 8 + (threadIdx.x >> 5);
    if (n >= N) return;
    int lane = threadIdx.x & 31;
    int beg = row_ptr[n];
    int end = row_ptr[n + 1];
    const uint2*  x2 = (const uint2*)xb;     // row = 32 uint2
    const float4* r4 = (const float4*)rel;   // row = 32 float4
    float4 s = make_float4(0.f, 0.f, 0.f, 0.f);
    int e = beg;
    for (; e + 3 < end; e += 4) {
        int c0 = col[e], c1 = col[e + 1], c2 = col[e + 2], c3 = col[e + 3];
        uint2  u0 = x2[(size_t)(c0 & 0x1FFFF) * 32 + lane];
        float4 r0 = r4[(size_t)(c0 >> 17) * 32 + lane];
        uint2  u1 = x2[(size_t)(c1 & 0x1FFFF) * 32 + lane];
        float4 r1 = r4[(size_t)(c1 >> 17) * 32 + lane];
        uint2  u2 = x2[(size_t)(c2 & 0x1FFFF) * 32 + lane];
        float4 r2 = r4[(size_t)(c2 >> 17) * 32 + lane];
        uint2  u3 = x2[(size_t)(c3 & 0x1FFFF) * 32 + lane];
        float4 r3 = r4[(size_t)(c3 >> 17) * 32 + lane];
        s.x += ((blo(u0.x) - r0.x) + (blo(u1.x) - r1.x)) + ((blo(u2.x) - r2.x) + (blo(u3.x) - r3.x));
        s.y += ((bhi(u0.x) - r0.y) + (bhi(u1.x) - r1.y)) + ((bhi(u2.x) - r2.y) + (bhi(u3.x) - r3.y));
        s.z += ((blo(u0.y) - r0.z) + (blo(u1.y) - r1.z)) + ((blo(u2.y) - r2.z) + (blo(u3.y) - r3.z));
        s.w += ((bhi(u0.y) - r0.w) + (bhi(u1.y) - r1.w)) + ((bhi(u2.y) - r2.w) + (bhi(u3.y) - r3.w));
    }
    for (; e < end; ++e) {
        int c = col[e];
        uint2  u = x2[(size_t)(c & 0x1FFFF) * 32 + lane];
        float4 r = r4[(size_t)(c >> 17) * 32 + lane];
        s.x += blo(u.x) - r.x;
        s.y += bhi(u.x) - r.y;
        s.z += blo(u.y) - r.z;
        s.w += bhi(u.y) - r.w;
    }
    ((float4*)agg)[(size_t)n * 32 + lane] = s;
}

// ---------------------------------------------------------------------------
// Node GEMM, k-chunked with BOTH operands in LDS:
//   out[n][j] = relu?( cvec[j] + sum_{k<256} A[n][k]*Wcat[k][j] )
// A = [agg (fp32) | x (fp32 layer1 / bf16 hb layer2)].
// Per 4-k step: 4 ds_read_b128 (W) + 4 ds_read_b128 (A, broadcast) : 64 FMA.
// LDS 40KB -> 4 blocks/CU. Weight traffic: 128KB/block (was 1MB).
// out may alias agg: each block reads only its own rows (into LDS, before any
// write) and writes only its own rows.
// ---------------------------------------------------------------------------
__global__ __launch_bounds__(256) void node_kernel(
    const float* __restrict__ agg,
    const float* __restrict__ xf,        // fp32 x-part or nullptr
    const unsigned* __restrict__ xb16,   // bf16 x-part or nullptr
    const float* __restrict__ Wcat,
    const float* __restrict__ cvec,
    float* __restrict__ outf,            // fp32 output or nullptr
    unsigned* __restrict__ outb,         // bf16 output or nullptr
    int do_relu, int N) {
    __shared__ float As[NPB][KC];        // 8 KB
    __shared__ float Ws[KC][D];          // 32 KB
    int tid = threadIdx.x;
    int nbase = blockIdx.x * NPB;
    int jq = tid & 31;        // col quad: cols 4jq..4jq+3
    int ng = tid >> 5;        // node group: nodes 4ng..4ng+3

    float4 cv = ((const float4*)cvec)[jq];
    float4 acc[4];
#pragma unroll
    for (int i = 0; i < 4; ++i) acc[i] = cv;

    for (int kc = 0; kc < 4; ++kc) {
        // ---- stage W chunk: rows kc*64..kc*64+63, coalesced 32KB ----
        const float4* Wg = (const float4*)(Wcat + (size_t)kc * KC * D);
        for (int i = tid; i < KC * (D / 4); i += 256)
            ((float4*)Ws)[i] = Wg[i];
        // ---- stage A chunk: 32 nodes x 64 k ----
        if (kc < 2) {
            const float* Ab = agg + (size_t)nbase * D + kc * KC;
            for (int i = tid; i < NPB * (KC / 4); i += 256) {
                int nn = i >> 4, q = i & 15;
                float4 v = make_float4(0.f, 0.f, 0.f, 0.f);
                if (nbase + nn < N) v = ((const float4*)(Ab + (size_t)nn * D))[q];
                *(float4*)&As[nn][q * 4] = v;
            }
        } else if (xf) {
            const float* Ab = xf + (size_t)nbase * D + (kc - 2) * KC;
            for (int i = tid; i < NPB * (KC / 4); i += 256) {
                int nn = i >> 4, q = i & 15;
                float4 v = make_float4(0.f, 0.f, 0.f, 0.f);
                if (nbase + nn < N) v = ((const float4*)(Ab + (size_t)nn * D))[q];
                *(float4*)&As[nn][q * 4] = v;
            }
        } else {
            // bf16 source: row = 64 uints; this chunk = 32 uints per node
            const unsigned* Hb = xb16 + (size_t)nbase * 64 + (kc - 2) * 32;
            for (int i = tid; i < NPB * 8; i += 256) {   // 256 uint4
                int nn = i >> 3, q = i & 7;
                uint4 u = make_uint4(0u, 0u, 0u, 0u);
                if (nbase + nn < N) u = ((const uint4*)(Hb + (size_t)nn * 64))[q];
                float4 v0 = make_float4(blo(u.x), bhi(u.x), blo(u.y), bhi(u.y));
                float4 v1 = make_float4(blo(u.z), bhi(u.z), blo(u.w), bhi(u.w));
                *(float4*)&As[nn][q * 8]     = v0;
                *(float4*)&As[nn][q * 8 + 4] = v1;
            }
        }
        __syncthreads();

        for (int k = 0; k < KC; k += 4) {
            float4 w0 = *(const float4*)&Ws[k][jq * 4];
            float4 w1 = *(const float4*)&Ws[k + 1][jq * 4];
            float4 w2 = *(const float4*)&Ws[k + 2][jq * 4];
            float4 w3 = *(const float4*)&Ws[k + 3][jq * 4];
#pragma unroll
            for (int i = 0; i < 4; ++i) {
                float4 a = *(const float4*)&As[ng * 4 + i][k];
                acc[i].x = fmaf(a.x, w0.x, acc[i].x);
                acc[i].y = fmaf(a.x, w0.y, acc[i].y);
                acc[i].z = fmaf(a.x, w0.z, acc[i].z);
                acc[i].w = fmaf(a.x, w0.w, acc[i].w);
                acc[i].x = fmaf(a.y, w1.x, acc[i].x);
                acc[i].y = fmaf(a.y, w1.y, acc[i].y);
                acc[i].z = fmaf(a.y, w1.z, acc[i].z);
                acc[i].w = fmaf(a.y, w1.w, acc[i].w);
                acc[i].x = fmaf(a.z, w2.x, acc[i].x);
                acc[i].y = fmaf(a.z, w2.y, acc[i].y);
                acc[i].z = fmaf(a.z, w2.z, acc[i].z);
                acc[i].w = fmaf(a.z, w2.w, acc[i].w);
                acc[i].x = fmaf(a.w, w3.x, acc[i].x);
                acc[i].y = fmaf(a.w, w3.y, acc[i].y);
                acc[i].z = fmaf(a.w, w3.z, acc[i].z);
                acc[i].w = fmaf(a.w, w3.w, acc[i].w);
            }
        }
        __syncthreads();
    }

#pragma unroll
    for (int i = 0; i < 4; ++i) {
        int n = nbase + ng * 4 + i;
        if (n < N) {
            float4 v = acc[i];
            if (do_relu) {
                v.x = fmaxf(v.x, 0.f); v.y = fmaxf(v.y, 0.f);
                v.z = fmaxf(v.z, 0.f); v.w = fmaxf(v.w, 0.f);
            }
            if (outf) ((float4*)outf)[(size_t)n * 32 + jq] = v;
            if (outb) {
                uint2 o;
                o.x = bpack(v.x, v.y);
                o.y = bpack(v.z, v.w);
                ((uint2*)outb)[(size_t)n * 32 + jq] = o;
            }
        }
    }
}

extern "C" void kernel_launch(void* const* d_in, const int* in_sizes, int n_in,
                              void* d_out, int out_size, void* d_ws, size_t ws_size,
                              hipStream_t stream) {
    const float* x    = (const float*)d_in[0];
    const int*   ei   = (const int*)d_in[1];
    const int*   et   = (const int*)d_in[2];
    const float* WI1  = (const float*)d_in[3];
    const float* WO1  = (const float*)d_in[4];
    const float* rel1 = (const float*)d_in[5];
    const float* b1   = (const float*)d_in[6];
    const float* WI2  = (const float*)d_in[7];
    const float* WO2  = (const float*)d_in[8];
    const float* rel2 = (const float*)d_in[9];
    const float* b2   = (const float*)d_in[10];

    const int E = in_sizes[2];          // 800000
    const int N = in_sizes[0] / D;      // 50000
    const int* src = ei;
    const int* dst = ei + E;

    // workspace layout (fp32 h eliminated; bf16 xb/hb instead)
    float*    ws    = (float*)d_ws;
    float*    Wcat1 = ws;                         // 256*128
    float*    Wcat2 = Wcat1 + 256 * D;
    float*    cvec1 = Wcat2 + 256 * D;            // 128
    float*    cvec2 = cvec1 + D;
    unsigned* xb    = (unsigned*)(cvec2 + D);     // N*64 uints (bf16 x)
    unsigned* hb    = xb + (size_t)N * 64;        // N*64 uints (bf16 h)
    int*      counts    = (int*)(hb + (size_t)N * 64);  // N
    int*      row_ptr   = counts + N;             // N+1 (pad 4)
    int*      cursor    = row_ptr + N + 4;        // N
    int*      blockSums = cursor + N;             // <=256
    int*      col       = blockSums + 256;        // E packed ints

    float* agg = (float*)d_out;                   // gather output lives in d_out

    const int eb = (E + 255) / 256;
    const int N4 = N / 4;                         // 12500
    const int nb = (N4 + 255) / 256;              // 49
    const int nd4 = N * D / 4;                    // 1.6M

    // ---- prep + CSR build ----
    hipMemsetAsync(counts, 0, (size_t)N * sizeof(int), stream);
    prep_w<<<dim3(128, 2), 256, 0, stream>>>(WI1, WO1, WI2, WO2, Wcat1, Wcat2);
    prep_c<<<1, 256, 0, stream>>>(WI1, b1, rel1, WI2, b2, rel2, cvec1, cvec2);
    conv_bf16<<<(nd4 + 255) / 256, 256, 0, stream>>>(x, xb, nd4);
    hist_kernel<<<eb, 256, 0, stream>>>(dst, counts, E);
    scan_a<<<nb, 256, 0, stream>>>(counts, row_ptr, blockSums, N4);
    scan_b<<<1, 256, 0, stream>>>(blockSums, nb);
    scan_c<<<nb, 256, 0, stream>>>(row_ptr, cursor, blockSums, N4, N, E);
    reorder_kernel<<<eb, 256, 0, stream>>>(src, dst, et, cursor, col, E);

    const int gather_blocks = (N + 7) / 8;
    const int node_blocks = (N + NPB - 1) / NPB;

    // ---- layer 1: gather from bf16 x; node reads fp32 x, emits bf16 hb ----
    gather_kernel<<<gather_blocks, 256, 0, stream>>>(xb, col, row_ptr, rel1, agg, N);
    node_kernel<<<node_blocks, 256, 0, stream>>>(agg, x, (const unsigned*)nullptr,
                                                 Wcat1, cvec1,
                                                 (float*)nullptr, hb, 1, N);

    // ---- layer 2: gather from bf16 hb; node x-part from hb, fp32 out ----
    gather_kernel<<<gather_blocks, 256, 0, stream>>>(hb, col, row_ptr, rel2, agg, N);
    node_kernel<<<node_blocks, 256, 0, stream>>>(agg, (const float*)nullptr, hb,
                                                 Wcat2, cvec2,
                                                 (float*)d_out, (unsigned*)nullptr, 0, N);
}

// Round 6
// 323.860 us; speedup vs baseline: 4.9895x; 1.2221x over previous
//
#include <hip/hip_runtime.h>

#define D 128

typedef __attribute__((ext_vector_type(8))) short short8;   // 8 bf16 (4 VGPRs)
typedef __attribute__((ext_vector_type(4))) float f32x4;    // MFMA acc

// bf16 helpers: packed storage = little-endian pairs in a uint (elem 2i = lo)
__device__ __forceinline__ float blo(unsigned w) { return __uint_as_float(w << 16); }
__device__ __forceinline__ float bhi(unsigned w) { return __uint_as_float(w & 0xFFFF0000u); }
__device__ __forceinline__ unsigned bpack(float a, float b) {   // RNE
    unsigned ua = __float_as_uint(a), ub = __float_as_uint(b);
    ua += 0x7FFFu + ((ua >> 16) & 1u);
    ub += 0x7FFFu + ((ub >> 16) & 1u);
    return (ua >> 16) | (ub & 0xFFFF0000u);
}

// ---------------------------------------------------------------------------
// prep_w: Wt[j][k] bf16, [128 j][256 k]:
//   k<128 : WI[j][k]            (agg part)
//   k>=128: WI[j][k'] + WO[j][k'] (x part, k'=k-128)
// Node GEMM = Wt (as MFMA A-operand) x A-rows (as B-operand).
// ---------------------------------------------------------------------------
__global__ void prep_w(const float* __restrict__ WI1, const float* __restrict__ WO1,
                       const float* __restrict__ WI2, const float* __restrict__ WO2,
                       unsigned* __restrict__ Wt1, unsigned* __restrict__ Wt2) {
    int idx = blockIdx.x * 256 + threadIdx.x;   // 0..16383 (128 j x 128 uints)
    int j = idx >> 7;
    int kk = idx & 127;                         // uint index; k0 = 2*kk
    const float* WI = blockIdx.y ? WI2 : WI1;
    const float* WO = blockIdx.y ? WO2 : WO1;
    unsigned* Wt = blockIdx.y ? Wt2 : Wt1;
    int k0 = kk * 2;
    float a, b;
    if (k0 < D) {
        a = WI[j * D + k0];
        b = WI[j * D + k0 + 1];
    } else {
        int kx = k0 - D;
        a = WI[j * D + kx]     + WO[j * D + kx];
        b = WI[j * D + kx + 1] + WO[j * D + kx + 1];
    }
    Wt[idx] = bpack(a, b);
}

// cvec[j] = b[j] - sum_k WI[j][k]*rel0[k]   (fp32, exact bias path)
__global__ void prep_c(const float* __restrict__ WI1, const float* __restrict__ b1,
                       const float* __restrict__ rel1,
                       const float* __restrict__ WI2, const float* __restrict__ b2,
                       const float* __restrict__ rel2,
                       float* __restrict__ c1, float* __restrict__ c2) {
    int tid = threadIdx.x;
    int layer = tid >> 7;
    int j = tid & (D - 1);
    const float* WI = layer ? WI2 : WI1;
    const float* b  = layer ? b2  : b1;
    const float* rl = layer ? rel2 : rel1;   // row 0
    float s = b[j];
    for (int k = 0; k < D; ++k) s = fmaf(-WI[j * D + k], rl[k], s);
    (layer ? c2 : c1)[j] = s;
}

// fp32 x -> bf16 x-part of A1 ([N][128] uints; x-part = uints 64..127)
__global__ __launch_bounds__(256) void conv_x(const float* __restrict__ x,
                                              unsigned* __restrict__ A1, int n32) {
    int idx = blockIdx.x * 256 + threadIdx.x;   // over N*32 float4s
    if (idx < n32) {
        int n = idx >> 5, q = idx & 31;
        float4 v = ((const float4*)x)[idx];
        uint2 o;
        o.x = bpack(v.x, v.y);
        o.y = bpack(v.z, v.w);
        *(uint2*)(A1 + (size_t)n * 128 + 64 + q * 2) = o;
    }
}

// rel1/rel2 fp32 -> bf16 [237][64] uints
__global__ __launch_bounds__(256) void conv_rel(const float* __restrict__ rel1,
                                                const float* __restrict__ rel2,
                                                unsigned* __restrict__ rb1,
                                                unsigned* __restrict__ rb2, int half) {
    int idx = blockIdx.x * 256 + threadIdx.x;
    if (idx < 2 * half) {
        const float* src = (idx < half) ? rel1 : rel2;
        unsigned* dst = (idx < half) ? rb1 : rb2;
        int k = (idx < half) ? idx : idx - half;
        float4 v = ((const float4*)src)[k];
        uint2 o;
        o.x = bpack(v.x, v.y);
        o.y = bpack(v.z, v.w);
        *(uint2*)(dst + (size_t)k * 2) = o;
    }
}

// ---------------------------------------------------------------------------
// CSR build
// ---------------------------------------------------------------------------
__global__ __launch_bounds__(256) void hist_kernel(const int* __restrict__ dst,
                                                   int* __restrict__ counts, int E) {
    int e = blockIdx.x * 256 + threadIdx.x;
    if (e < E) atomicAdd(&counts[dst[e]], 1);
}

__global__ __launch_bounds__(256) void scan_a(const int* __restrict__ counts,
                                              int* __restrict__ row_ptr,
                                              int* __restrict__ blockSums, int N4) {
    __shared__ int partial[256];
    int tid = threadIdx.x;
    int gi = blockIdx.x * 256 + tid;
    int4 c = make_int4(0, 0, 0, 0);
    if (gi < N4) c = ((const int4*)counts)[gi];
    int s = c.x + c.y + c.z + c.w;
    partial[tid] = s;
    __syncthreads();
    for (int off = 1; off < 256; off <<= 1) {
        int v = (tid >= off) ? partial[tid - off] : 0;
        __syncthreads();
        partial[tid] += v;
        __syncthreads();
    }
    int pre = (tid > 0) ? partial[tid - 1] : 0;
    if (gi < N4) {
        int4 o;
        o.x = pre;
        o.y = o.x + c.x;
        o.z = o.y + c.y;
        o.w = o.z + c.z;
        ((int4*)row_ptr)[gi] = o;
    }
    if (tid == 255) blockSums[blockIdx.x] = partial[255];
}

__global__ __launch_bounds__(256) void scan_b(int* __restrict__ blockSums, int nb) {
    __shared__ int partial[256];
    int tid = threadIdx.x;
    int orig = (tid < nb) ? blockSums[tid] : 0;
    partial[tid] = orig;
    __syncthreads();
    for (int off = 1; off < 256; off <<= 1) {
        int v = (tid >= off) ? partial[tid - off] : 0;
        __syncthreads();
        partial[tid] += v;
        __syncthreads();
    }
    if (tid < nb) blockSums[tid] = partial[tid] - orig;   // exclusive
}

__global__ __launch_bounds__(256) void scan_c(int* __restrict__ row_ptr,
                                              int* __restrict__ cursor,
                                              const int* __restrict__ blockSums,
                                              int N4, int N, int E) {
    int gi = blockIdx.x * 256 + threadIdx.x;
    int off = blockSums[blockIdx.x];
    if (gi < N4) {
        int4 v = ((int4*)row_ptr)[gi];
        v.x += off; v.y += off; v.z += off; v.w += off;
        ((int4*)row_ptr)[gi] = v;
        ((int4*)cursor)[gi] = v;
    }
    if (blockIdx.x == 0 && threadIdx.x == 0) row_ptr[N] = E;
}

// col packed: src | (etype << 17)
__global__ __launch_bounds__(256) void reorder_kernel(const int* __restrict__ src,
                                                      const int* __restrict__ dst,
                                                      const int* __restrict__ et,
                                                      int* __restrict__ cursor,
                                                      int* __restrict__ col, int E) {
    int e = blockIdx.x * 256 + threadIdx.x;
    if (e < E) {
        int pos = atomicAdd(&cursor[dst[e]], 1);
        col[pos] = src[e] | (et[e] << 17);
    }
}

// ---------------------------------------------------------------------------
// Gather (all bf16): agg[n] = sum_e (x[src_e] - rel[et_e]), fp32 accumulate.
// Reads x-part of Asrc rows (+64 uints); writes bf16 agg part of Adst rows.
// Half-wave (32 lanes) per node, uint2 (4 bf16) per lane, 4-edge unroll.
// ---------------------------------------------------------------------------
__global__ __launch_bounds__(256) void gather_kernel(const unsigned* __restrict__ Asrc,
                                                     const int* __restrict__ col,
                                                     const int* __restrict__ row_ptr,
                                                     const unsigned* __restrict__ relb,
                                                     unsigned* __restrict__ Adst, int N) {
    int n = blockIdx.x * 8 + (threadIdx.x >> 5);
    if (n >= N) return;
    int lane = threadIdx.x & 31;
    int beg = row_ptr[n];
    int end = row_ptr[n + 1];
    float4 s = make_float4(0.f, 0.f, 0.f, 0.f);
    int e = beg;
    for (; e + 3 < end; e += 4) {
        int c0 = col[e], c1 = col[e + 1], c2 = col[e + 2], c3 = col[e + 3];
        uint2 u0 = *(const uint2*)(Asrc + (size_t)(c0 & 0x1FFFF) * 128 + 64 + 2 * lane);
        uint2 r0 = *(const uint2*)(relb + (size_t)(c0 >> 17) * 64 + 2 * lane);
        uint2 u1 = *(const uint2*)(Asrc + (size_t)(c1 & 0x1FFFF) * 128 + 64 + 2 * lane);
        uint2 r1 = *(const uint2*)(relb + (size_t)(c1 >> 17) * 64 + 2 * lane);
        uint2 u2 = *(const uint2*)(Asrc + (size_t)(c2 & 0x1FFFF) * 128 + 64 + 2 * lane);
        uint2 r2 = *(const uint2*)(relb + (size_t)(c2 >> 17) * 64 + 2 * lane);
        uint2 u3 = *(const uint2*)(Asrc + (size_t)(c3 & 0x1FFFF) * 128 + 64 + 2 * lane);
        uint2 r3 = *(const uint2*)(relb + (size_t)(c3 >> 17) * 64 + 2 * lane);
        s.x += ((blo(u0.x) - blo(r0.x)) + (blo(u1.x) - blo(r1.x))) +
               ((blo(u2.x) - blo(r2.x)) + (blo(u3.x) - blo(r3.x)));
        s.y += ((bhi(u0.x) - bhi(r0.x)) + (bhi(u1.x) - bhi(r1.x))) +
               ((bhi(u2.x) - bhi(r2.x)) + (bhi(u3.x) - bhi(r3.x)));
        s.z += ((blo(u0.y) - blo(r0.y)) + (blo(u1.y) - blo(r1.y))) +
               ((blo(u2.y) - blo(r2.y)) + (blo(u3.y) - blo(r3.y)));
        s.w += ((bhi(u0.y) - bhi(r0.y)) + (bhi(u1.y) - bhi(r1.y))) +
               ((bhi(u2.y) - bhi(r2.y)) + (bhi(u3.y) - bhi(r3.y)));
    }
    for (; e < end; ++e) {
        int c = col[e];
        uint2 u = *(const uint2*)(Asrc + (size_t)(c & 0x1FFFF) * 128 + 64 + 2 * lane);
        uint2 r = *(const uint2*)(relb + (size_t)(c >> 17) * 64 + 2 * lane);
        s.x += blo(u.x) - blo(r.x);
        s.y += bhi(u.x) - bhi(r.x);
        s.z += blo(u.y) - blo(r.y);
        s.w += bhi(u.y) - bhi(r.y);
    }
    uint2 o;
    o.x = bpack(s.x, s.y);
    o.y = bpack(s.z, s.w);
    *(uint2*)(Adst + (size_t)n * 128 + 2 * lane) = o;
}

// ---------------------------------------------------------------------------
// MFMA node GEMM: out[n][j] = act( cvec[j] + sum_{k<256} A[n][k]*Wt[j][k] )
// A = [agg|x] bf16 [N][256]; Wt bf16 [128][256].
// MFMA 16x16x32_bf16: A-operand = Wt tile (m=j), B-operand = node rows (n).
// C/D: col=lane&15 (node), row=(lane>>4)*4+reg (j) -> lane stores 4 contiguous j.
// Block: 256 thr = 4 waves x 32 nodes = 128 nodes; K in 4 chunks of 64.
// LDS: W-chunk [128 j][64 k] + A-chunk [128 n][64 k], 16B groups XOR-swizzled
// (group g of row r at position g^(r&7)) -> conflict-free b128 reads/writes.
// NOTE: A may alias outf (layer 2, d_out): each block stages its own rows
// into LDS (all chunks) before its stores; no cross-block row sharing.
// ---------------------------------------------------------------------------
__global__ __launch_bounds__(256) void node_mfma(
    const unsigned* A,                  // [N][128] uints (bf16 [N][256])
    const unsigned* __restrict__ Wt,    // [128][64] uints (bf16 [128][256])
    const float* __restrict__ cvec,
    float* outf,                        // fp32 out (layer 2) or nullptr
    unsigned* __restrict__ outb,        // bf16 x-part of next A (layer 1) or nullptr
    int do_relu, int N) {
    __shared__ unsigned WtS[128 * 32];  // 16 KB
    __shared__ unsigned AS[128 * 32];   // 16 KB
    int tid = threadIdx.x;
    int w = tid >> 6;
    int lane = tid & 63;
    int m = lane & 15;
    int quad = lane >> 4;
    int nbase = blockIdx.x * 128;

    f32x4 acc[2][8];
#pragma unroll
    for (int nt = 0; nt < 2; ++nt)
#pragma unroll
        for (int t = 0; t < 8; ++t) acc[nt][t] = (f32x4)(0.f);

    for (int kc = 0; kc < 4; ++kc) {
        // stage W chunk (16 KB, coalesced; same for all blocks -> L2-hot)
        for (int i = tid; i < 1024; i += 256) {
            int j = i >> 3, q = i & 7;
            uint4 v = ((const uint4*)Wt)[j * 32 + kc * 8 + q];
            *(uint4*)&WtS[j * 32 + 4 * (q ^ (j & 7))] = v;
        }
        // stage A chunk (16 KB)
        for (int i = tid; i < 1024; i += 256) {
            int n = i >> 3, q = i & 7;
            int gn = nbase + n;
            uint4 v = make_uint4(0u, 0u, 0u, 0u);
            if (gn < N) v = ((const uint4*)A)[(size_t)gn * 32 + kc * 8 + q];
            *(uint4*)&AS[n * 32 + 4 * (q ^ (n & 7))] = v;
        }
        __syncthreads();

#pragma unroll
        for (int s = 0; s < 2; ++s) {
            int g = s * 4 + quad;
            int r0 = w * 32 + m;
            int r1 = r0 + 16;
            short8 b0 = *(const short8*)&AS[r0 * 32 + 4 * (g ^ (r0 & 7))];
            short8 b1 = *(const short8*)&AS[r1 * 32 + 4 * (g ^ (r1 & 7))];
#pragma unroll
            for (int t = 0; t < 8; ++t) {
                int jr = t * 16 + m;
                short8 a = *(const short8*)&WtS[jr * 32 + 4 * (g ^ (jr & 7))];
                acc[0][t] = __builtin_amdgcn_mfma_f32_16x16x32_bf16(a, b0, acc[0][t], 0, 0, 0);
                acc[1][t] = __builtin_amdgcn_mfma_f32_16x16x32_bf16(a, b1, acc[1][t], 0, 0, 0);
            }
        }
        __syncthreads();
    }

    // epilogue: lane holds, per tile t, j = t*16 + quad*4 + (0..3) for node col m
#pragma unroll
    for (int nt = 0; nt < 2; ++nt) {
        int node = nbase + w * 32 + nt * 16 + m;
        if (node < N) {
#pragma unroll
            for (int t = 0; t < 8; ++t) {
                float4 cv = ((const float4*)cvec)[t * 4 + quad];
                f32x4 a = acc[nt][t];
                float v0 = a[0] + cv.x;
                float v1 = a[1] + cv.y;
                float v2 = a[2] + cv.z;
                float v3 = a[3] + cv.w;
                if (do_relu) {
                    v0 = fmaxf(v0, 0.f); v1 = fmaxf(v1, 0.f);
                    v2 = fmaxf(v2, 0.f); v3 = fmaxf(v3, 0.f);
                }
                if (outf) {
                    ((float4*)outf)[(size_t)node * 32 + t * 4 + quad] =
                        make_float4(v0, v1, v2, v3);
                } else {
                    uint2 o;
                    o.x = bpack(v0, v1);
                    o.y = bpack(v2, v3);
                    ((uint2*)(outb + (size_t)node * 128))[32 + t * 4 + quad] = o;
                }
            }
        }
    }
}

extern "C" void kernel_launch(void* const* d_in, const int* in_sizes, int n_in,
                              void* d_out, int out_size, void* d_ws, size_t ws_size,
                              hipStream_t stream) {
    const float* x    = (const float*)d_in[0];
    const int*   ei   = (const int*)d_in[1];
    const int*   et   = (const int*)d_in[2];
    const float* WI1  = (const float*)d_in[3];
    const float* WO1  = (const float*)d_in[4];
    const float* rel1 = (const float*)d_in[5];
    const float* b1   = (const float*)d_in[6];
    const float* WI2  = (const float*)d_in[7];
    const float* WO2  = (const float*)d_in[8];
    const float* rel2 = (const float*)d_in[9];
    const float* b2   = (const float*)d_in[10];

    const int E = in_sizes[2];          // 800000
    const int N = in_sizes[0] / D;      // 50000
    const int* src = ei;
    const int* dst = ei + E;

    // workspace layout (uints), A2 lives in d_out
    unsigned* wsu  = (unsigned*)d_ws;
    unsigned* A1   = wsu;                          // N*128 uints (25.6 MB)
    unsigned* Wt1  = A1 + (size_t)N * 128;         // 16384
    unsigned* Wt2  = Wt1 + 16384;                  // 16384
    float*    cvec1 = (float*)(Wt2 + 16384);       // 128
    float*    cvec2 = cvec1 + D;                   // 128
    unsigned* rb1  = (unsigned*)(cvec2 + D);       // 237*64
    unsigned* rb2  = rb1 + 237 * 64;               // 237*64
    int*      counts    = (int*)(rb2 + 237 * 64);  // N
    int*      row_ptr   = counts + N;              // N+4
    int*      cursor    = row_ptr + N + 4;         // N
    int*      blockSums = cursor + N;              // 256
    int*      col       = blockSums + 256;         // E

    unsigned* A2 = (unsigned*)d_out;               // [N][128] uints, becomes fp32 out

    const int eb = (E + 255) / 256;
    const int N4 = N / 4;
    const int nb = (N4 + 255) / 256;
    const int relHalf = 237 * 32;                  // float4s per rel table

    // ---- prep + CSR build ----
    hipMemsetAsync(counts, 0, (size_t)N * sizeof(int), stream);
    prep_w<<<dim3(64, 2), 256, 0, stream>>>(WI1, WO1, WI2, WO2, Wt1, Wt2);
    prep_c<<<1, 256, 0, stream>>>(WI1, b1, rel1, WI2, b2, rel2, cvec1, cvec2);
    conv_x<<<(N * 32 + 255) / 256, 256, 0, stream>>>(x, A1, N * 32);
    conv_rel<<<(2 * relHalf + 255) / 256, 256, 0, stream>>>(rel1, rel2, rb1, rb2, relHalf);
    hist_kernel<<<eb, 256, 0, stream>>>(dst, counts, E);
    scan_a<<<nb, 256, 0, stream>>>(counts, row_ptr, blockSums, N4);
    scan_b<<<1, 256, 0, stream>>>(blockSums, nb);
    scan_c<<<nb, 256, 0, stream>>>(row_ptr, cursor, blockSums, N4, N, E);
    reorder_kernel<<<eb, 256, 0, stream>>>(src, dst, et, cursor, col, E);

    const int gather_blocks = (N + 7) / 8;
    const int node_blocks = (N + 127) / 128;       // 391

    // ---- layer 1: gather x-part of A1 -> agg part of A1; node -> x-part of A2
    gather_kernel<<<gather_blocks, 256, 0, stream>>>(A1, col, row_ptr, rb1, A1, N);
    node_mfma<<<node_blocks, 256, 0, stream>>>(A1, Wt1, cvec1,
                                               (float*)nullptr, A2, 1, N);

    // ---- layer 2: gather x-part of A2 -> agg part of A2; node -> fp32 d_out
    gather_kernel<<<gather_blocks, 256, 0, stream>>>(A2, col, row_ptr, rb2, A2, N);
    node_mfma<<<node_blocks, 256, 0, stream>>>(A2, Wt2, cvec2,
                                               (float*)d_out, (unsigned*)nullptr, 0, N);
}

// Round 7
// 317.782 us; speedup vs baseline: 5.0849x; 1.0191x over previous
//
#include <hip/hip_runtime.h>

#define D 128

typedef __attribute__((ext_vector_type(8))) short short8;   // 8 bf16 (4 VGPRs)
typedef __attribute__((ext_vector_type(4))) float f32x4;    // MFMA acc

// bf16 helpers: packed storage = little-endian pairs in a uint (elem 2i = lo)
__device__ __forceinline__ float blo(unsigned w) { return __uint_as_float(w << 16); }
__device__ __forceinline__ float bhi(unsigned w) { return __uint_as_float(w & 0xFFFF0000u); }
__device__ __forceinline__ unsigned bpack(float a, float b) {   // RNE
    unsigned ua = __float_as_uint(a), ub = __float_as_uint(b);
    ua += 0x7FFFu + ((ua >> 16) & 1u);
    ub += 0x7FFFu + ((ub >> 16) & 1u);
    return (ua >> 16) | (ub & 0xFFFF0000u);
}

// ---------------------------------------------------------------------------
// prep_w: Wt[j][k] bf16, [128 j][256 k]: k<128 -> WI[j][k]; k>=128 -> WI+WO.
// ---------------------------------------------------------------------------
__global__ void prep_w(const float* __restrict__ WI1, const float* __restrict__ WO1,
                       const float* __restrict__ WI2, const float* __restrict__ WO2,
                       unsigned* __restrict__ Wt1, unsigned* __restrict__ Wt2) {
    int idx = blockIdx.x * 256 + threadIdx.x;   // 0..16383 (128 j x 128 uints)
    int j = idx >> 7;
    int kk = idx & 127;
    const float* WI = blockIdx.y ? WI2 : WI1;
    const float* WO = blockIdx.y ? WO2 : WO1;
    unsigned* Wt = blockIdx.y ? Wt2 : Wt1;
    int k0 = kk * 2;
    float a, b;
    if (k0 < D) {
        a = WI[j * D + k0];
        b = WI[j * D + k0 + 1];
    } else {
        int kx = k0 - D;
        a = WI[j * D + kx]     + WO[j * D + kx];
        b = WI[j * D + kx + 1] + WO[j * D + kx + 1];
    }
    Wt[idx] = bpack(a, b);
}

// cvec[j] = b[j] - sum_k WI[j][k]*rel0[k]   (fp32, exact bias path)
__global__ void prep_c(const float* __restrict__ WI1, const float* __restrict__ b1,
                       const float* __restrict__ rel1,
                       const float* __restrict__ WI2, const float* __restrict__ b2,
                       const float* __restrict__ rel2,
                       float* __restrict__ c1, float* __restrict__ c2) {
    int tid = threadIdx.x;
    int layer = tid >> 7;
    int j = tid & (D - 1);
    const float* WI = layer ? WI2 : WI1;
    const float* b  = layer ? b2  : b1;
    const float* rl = layer ? rel2 : rel1;
    float s = b[j];
    for (int k = 0; k < D; ++k) s = fmaf(-WI[j * D + k], rl[k], s);
    (layer ? c2 : c1)[j] = s;
}

// fp32 x -> bf16 x-part of A1 ([N][128] uints; x-part = uints 64..127)
__global__ __launch_bounds__(256) void conv_x(const float* __restrict__ x,
                                              unsigned* __restrict__ A1, int n32) {
    int idx = blockIdx.x * 256 + threadIdx.x;
    if (idx < n32) {
        int n = idx >> 5, q = idx & 31;
        float4 v = ((const float4*)x)[idx];
        uint2 o;
        o.x = bpack(v.x, v.y);
        o.y = bpack(v.z, v.w);
        *(uint2*)(A1 + (size_t)n * 128 + 64 + q * 2) = o;
    }
}

// rel1/rel2 fp32 -> bf16 [237][64] uints
__global__ __launch_bounds__(256) void conv_rel(const float* __restrict__ rel1,
                                                const float* __restrict__ rel2,
                                                unsigned* __restrict__ rb1,
                                                unsigned* __restrict__ rb2, int half) {
    int idx = blockIdx.x * 256 + threadIdx.x;
    if (idx < 2 * half) {
        const float* src = (idx < half) ? rel1 : rel2;
        unsigned* dst = (idx < half) ? rb1 : rb2;
        int k = (idx < half) ? idx : idx - half;
        float4 v = ((const float4*)src)[k];
        uint2 o;
        o.x = bpack(v.x, v.y);
        o.y = bpack(v.z, v.w);
        *(uint2*)(dst + (size_t)k * 2) = o;
    }
}

// ---------------------------------------------------------------------------
// CSR build: hist -> scan -> bucket sort (coarse then fine)
// ---------------------------------------------------------------------------
__global__ __launch_bounds__(256) void hist_kernel(const int* __restrict__ dst,
                                                   int* __restrict__ counts, int E) {
    int e = blockIdx.x * 256 + threadIdx.x;
    if (e < E) atomicAdd(&counts[dst[e]], 1);
}

__global__ __launch_bounds__(256) void scan_a(const int* __restrict__ counts,
                                              int* __restrict__ row_ptr,
                                              int* __restrict__ blockSums, int N4) {
    __shared__ int partial[256];
    int tid = threadIdx.x;
    int gi = blockIdx.x * 256 + tid;
    int4 c = make_int4(0, 0, 0, 0);
    if (gi < N4) c = ((const int4*)counts)[gi];
    int s = c.x + c.y + c.z + c.w;
    partial[tid] = s;
    __syncthreads();
    for (int off = 1; off < 256; off <<= 1) {
        int v = (tid >= off) ? partial[tid - off] : 0;
        __syncthreads();
        partial[tid] += v;
        __syncthreads();
    }
    int pre = (tid > 0) ? partial[tid - 1] : 0;
    if (gi < N4) {
        int4 o;
        o.x = pre;
        o.y = o.x + c.x;
        o.z = o.y + c.y;
        o.w = o.z + c.z;
        ((int4*)row_ptr)[gi] = o;
    }
    if (tid == 255) blockSums[blockIdx.x] = partial[255];
}

__global__ __launch_bounds__(256) void scan_b(int* __restrict__ blockSums, int nb) {
    __shared__ int partial[256];
    int tid = threadIdx.x;
    int orig = (tid < nb) ? blockSums[tid] : 0;
    partial[tid] = orig;
    __syncthreads();
    for (int off = 1; off < 256; off <<= 1) {
        int v = (tid >= off) ? partial[tid - off] : 0;
        __syncthreads();
        partial[tid] += v;
        __syncthreads();
    }
    if (tid < nb) blockSums[tid] = partial[tid] - orig;   // exclusive
}

__global__ __launch_bounds__(256) void scan_c(int* __restrict__ row_ptr,
                                              const int* __restrict__ blockSums,
                                              int N4, int N, int E) {
    int gi = blockIdx.x * 256 + threadIdx.x;
    int off = blockSums[blockIdx.x];
    if (gi < N4) {
        int4 v = ((int4*)row_ptr)[gi];
        v.x += off; v.y += off; v.z += off; v.w += off;
        ((int4*)row_ptr)[gi] = v;
    }
    if (blockIdx.x == 0 && threadIdx.x == 0) row_ptr[N] = E;
}

// coarseCursor[c] = row_ptr[c*128]
__global__ void init_coarse(const int* __restrict__ row_ptr,
                            int* __restrict__ coarseCursor, int nCoarse) {
    int c = blockIdx.x * 256 + threadIdx.x;
    if (c < nCoarse) coarseCursor[c] = row_ptr[c << 7];
}

// ---------------------------------------------------------------------------
// bucket1: group edges by coarse bucket c = dst>>7 into bulk[] (regions given
// by row_ptr/coarseCursor). Payload = src | et<<17 | (dst&127)<<25 (32 bits).
// Per-block LDS hist + ONE global atomic per (block, nonempty bucket);
// writes are chunked-contiguous (kills the 4B-random-scatter write amp).
// Order within a bucket is arbitrary (sum is order-independent).
// ---------------------------------------------------------------------------
__global__ __launch_bounds__(256) void bucket1(const int* __restrict__ src,
                                               const int* __restrict__ dstA,
                                               const int* __restrict__ et,
                                               int* __restrict__ coarseCursor,
                                               unsigned* __restrict__ bulk,
                                               int E, int nCoarse) {
    __shared__ unsigned pay[1024];
    __shared__ unsigned short ck[1024];
    __shared__ int hist[400];
    __shared__ int base[400];
    int tid = threadIdx.x;
    int e0 = blockIdx.x * 1024;
    int cnt = E - e0; if (cnt > 1024) cnt = 1024;
    for (int i = tid; i < nCoarse; i += 256) hist[i] = 0;
    __syncthreads();
    for (int i = tid; i < cnt; i += 256) {
        int e = e0 + i;
        int d = dstA[e];
        pay[i] = (unsigned)src[e] | ((unsigned)et[e] << 17) | ((unsigned)(d & 127) << 25);
        int c = d >> 7;
        ck[i] = (unsigned short)c;
        atomicAdd(&hist[c], 1);
    }
    __syncthreads();
    for (int i = tid; i < nCoarse; i += 256) {
        int h = hist[i];
        base[i] = (h > 0) ? atomicAdd(&coarseCursor[i], h) : 0;
        hist[i] = 0;
    }
    __syncthreads();
    for (int i = tid; i < cnt; i += 256) {
        int c = ck[i];
        int pos = base[c] + atomicAdd(&hist[c], 1);
        bulk[pos] = pay[i];
    }
}

// ---------------------------------------------------------------------------
// bucket2: one block per coarse bucket; place edges at final CSR slots via
// 128 LDS cursors (init from row_ptr). All writes land in the bucket's own
// contiguous ~8KB region of col -> L2-hot, single-XCD.
// ---------------------------------------------------------------------------
__global__ __launch_bounds__(256) void bucket2(const unsigned* __restrict__ bulk,
                                               const int* __restrict__ row_ptr,
                                               int* __restrict__ col, int N) {
    __shared__ int cur[128];
    int c = blockIdx.x;
    int tid = threadIdx.x;
    int d0 = c << 7;
    int dEnd = d0 + 128; if (dEnd > N) dEnd = N;
    int base = row_ptr[d0];
    int end  = row_ptr[dEnd];
    if (tid < 128) {
        int d = d0 + tid;
        cur[tid] = (d < N) ? row_ptr[d] : 0;
    }
    __syncthreads();
    for (int i = base + tid; i < end; i += 256) {
        unsigned v = bulk[i];
        int f = v >> 25;
        int pos = atomicAdd(&cur[f], 1);
        col[pos] = (int)(v & 0x1FFFFFFu);
    }
}

// ---------------------------------------------------------------------------
// Gather (all bf16): agg[n] = sum_e (x[src_e] - rel[et_e]), fp32 accumulate.
// Half-wave (32 lanes) per node, uint2 (4 bf16) per lane, 8-edge unroll
// (16 outstanding 8B loads/lane on the L3-latency chain).
// ---------------------------------------------------------------------------
__global__ __launch_bounds__(256) void gather_kernel(const unsigned* __restrict__ Asrc,
                                                     const int* __restrict__ col,
                                                     const int* __restrict__ row_ptr,
                                                     const unsigned* __restrict__ relb,
                                                     unsigned* __restrict__ Adst, int N) {
    int n = blockIdx.x * 8 + (threadIdx.x >> 5);
    if (n >= N) return;
    int lane = threadIdx.x & 31;
    int beg = row_ptr[n];
    int end = row_ptr[n + 1];
    float4 s = make_float4(0.f, 0.f, 0.f, 0.f);
    int e = beg;
    for (; e + 7 < end; e += 8) {
        uint2 u[8], r[8];
#pragma unroll
        for (int t = 0; t < 8; ++t) {
            int c = col[e + t];
            u[t] = *(const uint2*)(Asrc + (size_t)(c & 0x1FFFF) * 128 + 64 + 2 * lane);
            r[t] = *(const uint2*)(relb + (size_t)(c >> 17) * 64 + 2 * lane);
        }
#pragma unroll
        for (int t = 0; t < 8; ++t) {
            s.x += blo(u[t].x) - blo(r[t].x);
            s.y += bhi(u[t].x) - bhi(r[t].x);
            s.z += blo(u[t].y) - blo(r[t].y);
            s.w += bhi(u[t].y) - bhi(r[t].y);
        }
    }
    for (; e + 1 < end; e += 2) {
        int c0 = col[e], c1 = col[e + 1];
        uint2 u0 = *(const uint2*)(Asrc + (size_t)(c0 & 0x1FFFF) * 128 + 64 + 2 * lane);
        uint2 r0 = *(const uint2*)(relb + (size_t)(c0 >> 17) * 64 + 2 * lane);
        uint2 u1 = *(const uint2*)(Asrc + (size_t)(c1 & 0x1FFFF) * 128 + 64 + 2 * lane);
        uint2 r1 = *(const uint2*)(relb + (size_t)(c1 >> 17) * 64 + 2 * lane);
        s.x += (blo(u0.x) - blo(r0.x)) + (blo(u1.x) - blo(r1.x));
        s.y += (bhi(u0.x) - bhi(r0.x)) + (bhi(u1.x) - bhi(r1.x));
        s.z += (blo(u0.y) - blo(r0.y)) + (blo(u1.y) - blo(r1.y));
        s.w += (bhi(u0.y) - bhi(r0.y)) + (bhi(u1.y) - bhi(r1.y));
    }
    if (e < end) {
        int c = col[e];
        uint2 u = *(const uint2*)(Asrc + (size_t)(c & 0x1FFFF) * 128 + 64 + 2 * lane);
        uint2 r = *(const uint2*)(relb + (size_t)(c >> 17) * 64 + 2 * lane);
        s.x += blo(u.x) - blo(r.x);
        s.y += bhi(u.x) - bhi(r.x);
        s.z += blo(u.y) - blo(r.y);
        s.w += bhi(u.y) - bhi(r.y);
    }
    uint2 o;
    o.x = bpack(s.x, s.y);
    o.y = bpack(s.z, s.w);
    *(uint2*)(Adst + (size_t)n * 128 + 2 * lane) = o;
}

// ---------------------------------------------------------------------------
// MFMA node GEMM: out[n][j] = act( cvec[j] + sum_{k<256} A[n][k]*Wt[j][k] )
// (See round-6 comments; unchanged.)
// ---------------------------------------------------------------------------
__global__ __launch_bounds__(256) void node_mfma(
    const unsigned* A,                  // [N][128] uints (bf16 [N][256])
    const unsigned* __restrict__ Wt,    // [128][64] uints (bf16 [128][256])
    const float* __restrict__ cvec,
    float* outf,                        // fp32 out (layer 2) or nullptr
    unsigned* __restrict__ outb,        // bf16 x-part of next A (layer 1) or nullptr
    int do_relu, int N) {
    __shared__ unsigned WtS[128 * 32];  // 16 KB
    __shared__ unsigned AS[128 * 32];   // 16 KB
    int tid = threadIdx.x;
    int w = tid >> 6;
    int lane = tid & 63;
    int m = lane & 15;
    int quad = lane >> 4;
    int nbase = blockIdx.x * 128;

    f32x4 acc[2][8];
#pragma unroll
    for (int nt = 0; nt < 2; ++nt)
#pragma unroll
        for (int t = 0; t < 8; ++t) acc[nt][t] = (f32x4)(0.f);

    for (int kc = 0; kc < 4; ++kc) {
        for (int i = tid; i < 1024; i += 256) {
            int j = i >> 3, q = i & 7;
            uint4 v = ((const uint4*)Wt)[j * 32 + kc * 8 + q];
            *(uint4*)&WtS[j * 32 + 4 * (q ^ (j & 7))] = v;
        }
        for (int i = tid; i < 1024; i += 256) {
            int n = i >> 3, q = i & 7;
            int gn = nbase + n;
            uint4 v = make_uint4(0u, 0u, 0u, 0u);
            if (gn < N) v = ((const uint4*)A)[(size_t)gn * 32 + kc * 8 + q];
            *(uint4*)&AS[n * 32 + 4 * (q ^ (n & 7))] = v;
        }
        __syncthreads();

#pragma unroll
        for (int s = 0; s < 2; ++s) {
            int g = s * 4 + quad;
            int r0 = w * 32 + m;
            int r1 = r0 + 16;
            short8 b0 = *(const short8*)&AS[r0 * 32 + 4 * (g ^ (r0 & 7))];
            short8 b1 = *(const short8*)&AS[r1 * 32 + 4 * (g ^ (r1 & 7))];
#pragma unroll
            for (int t = 0; t < 8; ++t) {
                int jr = t * 16 + m;
                short8 a = *(const short8*)&WtS[jr * 32 + 4 * (g ^ (jr & 7))];
                acc[0][t] = __builtin_amdgcn_mfma_f32_16x16x32_bf16(a, b0, acc[0][t], 0, 0, 0);
                acc[1][t] = __builtin_amdgcn_mfma_f32_16x16x32_bf16(a, b1, acc[1][t], 0, 0, 0);
            }
        }
        __syncthreads();
    }

#pragma unroll
    for (int nt = 0; nt < 2; ++nt) {
        int node = nbase + w * 32 + nt * 16 + m;
        if (node < N) {
#pragma unroll
            for (int t = 0; t < 8; ++t) {
                float4 cv = ((const float4*)cvec)[t * 4 + quad];
                f32x4 a = acc[nt][t];
                float v0 = a[0] + cv.x;
                float v1 = a[1] + cv.y;
                float v2 = a[2] + cv.z;
                float v3 = a[3] + cv.w;
                if (do_relu) {
                    v0 = fmaxf(v0, 0.f); v1 = fmaxf(v1, 0.f);
                    v2 = fmaxf(v2, 0.f); v3 = fmaxf(v3, 0.f);
                }
                if (outf) {
                    ((float4*)outf)[(size_t)node * 32 + t * 4 + quad] =
                        make_float4(v0, v1, v2, v3);
                } else {
                    uint2 o;
                    o.x = bpack(v0, v1);
                    o.y = bpack(v2, v3);
                    ((uint2*)(outb + (size_t)node * 128))[32 + t * 4 + quad] = o;
                }
            }
        }
    }
}

extern "C" void kernel_launch(void* const* d_in, const int* in_sizes, int n_in,
                              void* d_out, int out_size, void* d_ws, size_t ws_size,
                              hipStream_t stream) {
    const float* x    = (const float*)d_in[0];
    const int*   ei   = (const int*)d_in[1];
    const int*   et   = (const int*)d_in[2];
    const float* WI1  = (const float*)d_in[3];
    const float* WO1  = (const float*)d_in[4];
    const float* rel1 = (const float*)d_in[5];
    const float* b1   = (const float*)d_in[6];
    const float* WI2  = (const float*)d_in[7];
    const float* WO2  = (const float*)d_in[8];
    const float* rel2 = (const float*)d_in[9];
    const float* b2   = (const float*)d_in[10];

    const int E = in_sizes[2];          // 800000
    const int N = in_sizes[0] / D;      // 50000
    const int* src = ei;
    const int* dst = ei + E;
    const int nCoarse = (N + 127) / 128;   // 391

    // workspace layout (uints), A2 lives in d_out
    unsigned* wsu  = (unsigned*)d_ws;
    unsigned* A1   = wsu;                          // N*128 uints (25.6 MB)
    unsigned* Wt1  = A1 + (size_t)N * 128;         // 16384
    unsigned* Wt2  = Wt1 + 16384;                  // 16384
    float*    cvec1 = (float*)(Wt2 + 16384);       // 128
    float*    cvec2 = cvec1 + D;                   // 128
    unsigned* rb1  = (unsigned*)(cvec2 + D);       // 237*64
    unsigned* rb2  = rb1 + 237 * 64;               // 237*64
    int*      counts    = (int*)(rb2 + 237 * 64);  // N
    int*      row_ptr   = counts + N;              // N+4
    int*      blockSums = row_ptr + N + 4;         // 256
    int*      coarseCur = blockSums + 256;         // nCoarse (+pad)
    int*      col       = coarseCur + 512;         // E
    unsigned* bulk      = (unsigned*)(col + E);    // E

    unsigned* A2 = (unsigned*)d_out;               // [N][128] uints, becomes fp32 out

    const int eb = (E + 255) / 256;
    const int N4 = N / 4;
    const int nb = (N4 + 255) / 256;
    const int relHalf = 237 * 32;

    // ---- prep + CSR build ----
    hipMemsetAsync(counts, 0, (size_t)N * sizeof(int), stream);
    prep_w<<<dim3(64, 2), 256, 0, stream>>>(WI1, WO1, WI2, WO2, Wt1, Wt2);
    prep_c<<<1, 256, 0, stream>>>(WI1, b1, rel1, WI2, b2, rel2, cvec1, cvec2);
    conv_x<<<(N * 32 + 255) / 256, 256, 0, stream>>>(x, A1, N * 32);
    conv_rel<<<(2 * relHalf + 255) / 256, 256, 0, stream>>>(rel1, rel2, rb1, rb2, relHalf);
    hist_kernel<<<eb, 256, 0, stream>>>(dst, counts, E);
    scan_a<<<nb, 256, 0, stream>>>(counts, row_ptr, blockSums, N4);
    scan_b<<<1, 256, 0, stream>>>(blockSums, nb);
    scan_c<<<nb, 256, 0, stream>>>(row_ptr, blockSums, N4, N, E);
    init_coarse<<<(nCoarse + 255) / 256, 256, 0, stream>>>(row_ptr, coarseCur, nCoarse);
    bucket1<<<(E + 1023) / 1024, 256, 0, stream>>>(src, dst, et, coarseCur, bulk, E, nCoarse);
    bucket2<<<nCoarse, 256, 0, stream>>>(bulk, row_ptr, col, N);

    const int gather_blocks = (N + 7) / 8;
    const int node_blocks = (N + 127) / 128;       // 391

    // ---- layer 1: gather x-part of A1 -> agg part of A1; node -> x-part of A2
    gather_kernel<<<gather_blocks, 256, 0, stream>>>(A1, col, row_ptr, rb1, A1, N);
    node_mfma<<<node_blocks, 256, 0, stream>>>(A1, Wt1, cvec1,
                                               (float*)nullptr, A2, 1, N);

    // ---- layer 2: gather x-part of A2 -> agg part of A2; node -> fp32 d_out
    gather_kernel<<<gather_blocks, 256, 0, stream>>>(A2, col, row_ptr, rb2, A2, N);
    node_mfma<<<node_blocks, 256, 0, stream>>>(A2, Wt2, cvec2,
                                               (float*)d_out, (unsigned*)nullptr, 0, N);
}